// Round 2
// baseline (662.867 us; speedup 1.0000x reference)
//
#include <hip/hip_runtime.h>

#define NB 64
#define T 320
#define D 768
#define WD 32
#define NSTEP (2 * T - 1)
#define CH 16
#define BIG 1e30f

// ---------------- K1: projection  xw = x @ Weff^T + beff ----------------
__global__ __launch_bounds__(256) void proj_kernel(
    const float* __restrict__ x, const float* __restrict__ y,
    const float* __restrict__ W, const float* __restrict__ bias,
    const float* __restrict__ wscale, const float* __restrict__ wshift,
    float* __restrict__ xw, float* __restrict__ yw) {
  __shared__ __align__(16) float Wl[WD * D];
  int tid = threadIdx.x;
  for (int i = tid; i < WD * D; i += 256) {
    int k = i / D;
    Wl[i] = W[i] * wscale[k];
  }
  __syncthreads();
  int r = blockIdx.x * 256 + tid;  // 0..2*NB*T-1
  const float* src;
  float* dst;
  if (r < NB * T) { src = x + (size_t)r * D; dst = xw + (size_t)r * WD; }
  else            { src = y + (size_t)(r - NB * T) * D; dst = yw + (size_t)(r - NB * T) * WD; }
  float acc[WD];
#pragma unroll
  for (int k = 0; k < WD; ++k) acc[k] = 0.f;
  const float4* s4 = (const float4*)src;
  const float4* W4 = (const float4*)Wl;
  for (int c = 0; c < D / 4; ++c) {
    float4 xv = s4[c];
#pragma unroll
    for (int k = 0; k < WD; ++k) {
      float4 wv = W4[k * (D / 4) + c];
      acc[k] += xv.x * wv.x + xv.y * wv.y + xv.z * wv.z + xv.w * wv.w;
    }
  }
#pragma unroll
  for (int k = 0; k < WD; ++k) {
    float be = bias[k] * wscale[k] + wshift[k];
    dst[k] = acc[k] + be;
  }
}

// ---------------- K2: banded soft-DTW, wave-serial DP + dist producers ----------------
// Block = 5 waves per batch. Wave 0 runs the DP chain entirely in registers with
// __shfl neighbor exchange (no barrier on the chain). Waves 1-4 produce banded
// squared distances for future steps into an LDS ring; sync every CH steps.
// Slot m = t2 - t1 + 81 in [0,162); step d activates parity (d+1)&1.
// Lane l owns slot-pair a=l (slots 2l,2l+1); lanes 0..16 also own a=l+64.
__global__ __launch_bounds__(320) void dtw_kernel(
    const float* __restrict__ xw, const float* __restrict__ yw,
    float* __restrict__ valbuf) {
  __shared__ float x2s[T], y2s[T];
  __shared__ float ring[32][162];
  int b = blockIdx.x;
  int tid = threadIdx.x;
  const float* xwb = xw + (size_t)b * T * WD;
  const float* ywb = yw + (size_t)b * T * WD;
  for (int i = tid; i < T; i += 320) {
    const float4* xr = (const float4*)(xwb + i * WD);
    const float4* yr = (const float4*)(ywb + i * WD);
    float sx = 0.f, sy = 0.f;
#pragma unroll
    for (int q = 0; q < 8; ++q) {
      float4 xv = xr[q], yv = yr[q];
      sx += xv.x * xv.x + xv.y * xv.y + xv.z * xv.z + xv.w * xv.w;
      sy += yv.x * yv.x + yv.y * yv.y + yv.z * yv.z + yv.w * yv.w;
    }
    x2s[i] = sx; y2s[i] = sy;
  }
  __syncthreads();

  auto produce = [&](int e0) {
    int tp = tid - 64;
    int e1 = e0 + CH; if (e1 > NSTEP) e1 = NSTEP;
    int ncell = (e1 - e0) * 81;
    for (int i = tp; i < ncell; i += 256) {
      int dd = (int)((unsigned)i / 81u);
      int a = i - dd * 81;
      int d = e0 + dd;
      int par = (d + 1) & 1;
      int t1 = ((d + 81 - par) >> 1) - a;
      int t2 = d - t1;
      if ((unsigned)t1 >= (unsigned)T || (unsigned)t2 >= (unsigned)T) continue;
      const float4* xr = (const float4*)(xwb + t1 * WD);
      const float4* yr = (const float4*)(ywb + t2 * WD);
      float dot = 0.f;
#pragma unroll
      for (int q = 0; q < 8; ++q) {
        float4 xv = xr[q], yv = yr[q];
        dot += xv.x * yv.x + xv.y * yv.y + xv.z * yv.z + xv.w * yv.w;
      }
      ring[d & 31][2 * a + par] = x2s[t1] + y2s[t2] - 2.f * dot;
    }
  };

  if (tid >= 64) produce(0);
  __syncthreads();

  float vA = 0.f, vB = 0.f, vA2 = 0.f, vB2 = 0.f;
  int l = tid;
  float* outb = valbuf + (size_t)b * T * T;

  for (int e0 = 0; e0 < NSTEP; e0 += CH) {
    if (tid >= 64) {
      if (e0 + CH < NSTEP) produce(e0 + CH);
    } else {
      int e1 = e0 + CH; if (e1 > NSTEP) e1 = NSTEP;
      for (int d = e0; d < e1; ++d) {
        int par = (d + 1) & 1;
        int base = (d + 81 - par) >> 1;
        int t1 = base - l;
        int t2 = d - t1;
        int m1 = 2 * l + par;
        bool v1 = ((unsigned)t1 < (unsigned)T) && ((unsigned)t2 < (unsigned)T);
        float sh1, sh2;
        if (par == 0) {
          // left neighbors (slot m-1, step d-1)
          sh1 = __shfl(vB, (l - 1) & 63);
          sh2 = __shfl((l == 63) ? vB : vB2, (l - 1) & 63);
        } else {
          // up neighbors (slot m+1, step d-1)
          sh1 = __shfl((l == 0) ? vA2 : vA, (l + 1) & 63);
          sh2 = __shfl(vA2, (l + 1) & 63);
        }
        // ---- primary cell (a = l) ----
        float dist1 = ring[d & 31][m1];
        float upv, lfv, dgv;
        if (par == 0) { upv = vB;  lfv = (l == 0) ? 0.f : sh1; dgv = vA; }
        else          { upv = sh1; lfv = vA;                   dgv = vB; }
        float cu = (t1 > 0) ? upv : BIG;
        float cl = (t2 > 0) ? lfv : BIG;
        float cd = (t1 > 0 && t2 > 0) ? dgv : BIG;
        float mn = fminf(fminf(cu, cl), cd);
        float mx = fmaxf(fmaxf(cu, cl), cd);
        float md = fmaxf(fminf(cu, cl), fminf(fmaxf(cu, cl), cd));
        float s1 = 1.f + __expf(mn - md) + __expf(mn - mx);
        float val1 = dist1 + mn - __logf(s1);
        if (d == 0) val1 = dist1;  // cell (0,0): no softmin term
        if (par == 0) vA = v1 ? val1 : vA; else vB = v1 ? val1 : vB;
        if (v1) outb[t1 * (T - 1) + d] = val1;
        // ---- second cell (a = l + 64), lanes 0..16 ----
        if (l < 17) {
          int t1b = t1 - 64;
          int t2b = d - t1b;
          int m2 = m1 + 128;
          bool v2 = ((unsigned)t1b < (unsigned)T) && ((unsigned)t2b < (unsigned)T);
          float dist2 = ring[d & 31][m2];
          float upv2, lfv2, dgv2;
          if (par == 0) { upv2 = vB2;                     lfv2 = sh2; dgv2 = vA2; }
          else          { upv2 = (l == 16) ? 0.f : sh2;  lfv2 = vA2; dgv2 = vB2; }
          float cu2 = (t1b > 0) ? upv2 : BIG;
          float cl2 = (t2b > 0) ? lfv2 : BIG;
          float cd2 = (t1b > 0 && t2b > 0) ? dgv2 : BIG;
          float mn2 = fminf(fminf(cu2, cl2), cd2);
          float mx2 = fmaxf(fmaxf(cu2, cl2), cd2);
          float md2 = fmaxf(fminf(cu2, cl2), fminf(fmaxf(cu2, cl2), cd2));
          float s2 = 1.f + __expf(mn2 - md2) + __expf(mn2 - mx2);
          float val2 = dist2 + mn2 - __logf(s2);
          if (par == 0) vA2 = v2 ? val2 : vA2; else vB2 = v2 ? val2 : vB2;
          if (v2) outb[t1b * (T - 1) + d] = val2;
        }
      }
    }
    __syncthreads();
  }
}

// ---------------- K3: row softmax of -val, band-masked read, in place ----------------
__global__ __launch_bounds__(T) void softmax_kernel(float* __restrict__ path) {
  __shared__ float sm1[5], sm2[5];
  int row = blockIdx.x;
  int t1 = row % T;
  int j = threadIdx.x;
  float* p = path + (size_t)row * T;
  bool in = (j >= t1 - 81) && (j <= t1 + 80);
  float v = in ? p[j] : 0.f;  // out-of-band cells are exact 0 in the reference
  float m = v;
#pragma unroll
  for (int off = 32; off >= 1; off >>= 1) m = fminf(m, __shfl_xor(m, off, 64));
  int w = j >> 6;
  if ((j & 63) == 0) sm1[w] = m;
  __syncthreads();
  m = fminf(fminf(fminf(sm1[0], sm1[1]), fminf(sm1[2], sm1[3])), sm1[4]);
  float e = __expf(m - v);  // exp(-v - max(-v))
  float s = e;
#pragma unroll
  for (int off = 32; off >= 1; off >>= 1) s += __shfl_xor(s, off, 64);
  if ((j & 63) == 0) sm2[w] = s;
  __syncthreads();
  s = sm2[0] + sm2[1] + sm2[2] + sm2[3] + sm2[4];
  p[j] = e / s;
}

// ---------------- K3b: column sums -> scale = 1/(colsum+1e-10) ----------------
__global__ __launch_bounds__(T) void colsum_kernel(
    const float* __restrict__ path, float* __restrict__ scale) {
  int b = blockIdx.x;
  int j = threadIdx.x;
  const float* p = path + (size_t)b * T * T;
  float s = 0.f;
  for (int t = 0; t < T; ++t) s += p[(size_t)t * T + j];
  scale[b * T + j] = 1.f / (s + 1e-10f);
}

// ---------------- K4: aligned[b,s,d] = scale[b,s] * sum_t P[b,t,s]*x[b,t,d] ----------------
#define TS 64
#define TDD 128
#define TK 16
__global__ __launch_bounds__(256) void bmm_kernel(
    const float* __restrict__ path, const float* __restrict__ x,
    const float* __restrict__ scale, float* __restrict__ out) {
  __shared__ __align__(16) float Pl[TK][TS];
  __shared__ __align__(16) float Xl[TK][TDD];
  int b = blockIdx.z;
  int s0 = blockIdx.y * TS;
  int d0 = blockIdx.x * TDD;
  int tid = threadIdx.x;
  int ts = tid & 15, td = tid >> 4;
  const float* pb = path + (size_t)b * T * T;
  const float* xb = x + (size_t)b * T * D;
  float acc[4][8];
#pragma unroll
  for (int i = 0; i < 4; ++i)
#pragma unroll
    for (int jj = 0; jj < 8; ++jj) acc[i][jj] = 0.f;
  for (int t0 = 0; t0 < T; t0 += TK) {
    __syncthreads();
    {  // stage P: 16x64
      int tr = tid >> 4;
      int sc = (tid & 15) * 4;
      *((float4*)&Pl[tr][sc]) = *((const float4*)&pb[(size_t)(t0 + tr) * T + s0 + sc]);
    }
    {  // stage X: 16x128
      int tr = tid >> 5;
      int dc = (tid & 31) * 4;
      *((float4*)&Xl[tr][dc]) = *((const float4*)&xb[(size_t)(t0 + tr) * D + d0 + dc]);
      *((float4*)&Xl[tr + 8][dc]) = *((const float4*)&xb[(size_t)(t0 + tr + 8) * D + d0 + dc]);
    }
    __syncthreads();
#pragma unroll
    for (int t = 0; t < TK; ++t) {
      float4 pv = *((const float4*)&Pl[t][ts * 4]);
      float4 xa = *((const float4*)&Xl[t][td * 8]);
      float4 xc = *((const float4*)&Xl[t][td * 8 + 4]);
      float pvv[4] = {pv.x, pv.y, pv.z, pv.w};
      float xvv[8] = {xa.x, xa.y, xa.z, xa.w, xc.x, xc.y, xc.z, xc.w};
#pragma unroll
      for (int i = 0; i < 4; ++i)
#pragma unroll
        for (int jj = 0; jj < 8; ++jj) acc[i][jj] += pvv[i] * xvv[jj];
    }
  }
#pragma unroll
  for (int i = 0; i < 4; ++i) {
    int s = s0 + ts * 4 + i;
    float sc = scale[b * T + s];
    float4 o0, o1;
    o0.x = acc[i][0] * sc; o0.y = acc[i][1] * sc; o0.z = acc[i][2] * sc; o0.w = acc[i][3] * sc;
    o1.x = acc[i][4] * sc; o1.y = acc[i][5] * sc; o1.z = acc[i][6] * sc; o1.w = acc[i][7] * sc;
    float* op = out + ((size_t)b * T + s) * D + d0 + td * 8;
    *((float4*)op) = o0;
    *((float4*)(op + 4)) = o1;
  }
}

extern "C" void kernel_launch(void* const* d_in, const int* in_sizes, int n_in,
                              void* d_out, int out_size, void* d_ws, size_t ws_size,
                              hipStream_t stream) {
  const float* x = (const float*)d_in[0];
  const float* y = (const float*)d_in[1];
  const float* W = (const float*)d_in[2];
  const float* bias = (const float*)d_in[3];
  const float* wscale = (const float*)d_in[4];
  const float* wshift = (const float*)d_in[5];
  float* outp = (float*)d_out;
  float* aligned = outp;                          // [B,T,D]
  float* path = outp + (size_t)NB * T * D;        // [B,T,T] (raw vals -> probs in place)
  float* ws = (float*)d_ws;
  float* xw = ws;
  float* yw = xw + (size_t)NB * T * WD;
  float* scale = yw + (size_t)NB * T * WD;        // [B,T]

  proj_kernel<<<dim3((2 * NB * T) / 256), 256, 0, stream>>>(x, y, W, bias, wscale, wshift, xw, yw);
  dtw_kernel<<<dim3(NB), 320, 0, stream>>>(xw, yw, path);
  softmax_kernel<<<dim3(NB * T), T, 0, stream>>>(path);
  colsum_kernel<<<dim3(NB), T, 0, stream>>>(path, scale);
  bmm_kernel<<<dim3(D / TDD, T / TS, NB), 256, 0, stream>>>(path, x, scale, aligned);
}

// Round 3
// 574.491 us; speedup vs baseline: 1.1538x; 1.1538x over previous
//
#include <hip/hip_runtime.h>

#define NB 64
#define T 320
#define D 768
#define WD 32
#define NSTEP 639
#define NCELL (NSTEP * 81)
#define BIG 1e30f

// ---------------- K1: projection  xw = x @ Weff^T + beff ----------------
__global__ __launch_bounds__(256) void proj_kernel(
    const float* __restrict__ x, const float* __restrict__ y,
    const float* __restrict__ W, const float* __restrict__ bias,
    const float* __restrict__ wscale, const float* __restrict__ wshift,
    float* __restrict__ xw, float* __restrict__ yw) {
  __shared__ __align__(16) float Wl[WD * D];
  int tid = threadIdx.x;
  for (int i = tid; i < WD * D; i += 256) {
    int k = i / D;
    Wl[i] = W[i] * wscale[k];
  }
  __syncthreads();
  int r = blockIdx.x * 256 + tid;
  const float* src;
  float* dst;
  if (r < NB * T) { src = x + (size_t)r * D; dst = xw + (size_t)r * WD; }
  else            { src = y + (size_t)(r - NB * T) * D; dst = yw + (size_t)(r - NB * T) * WD; }
  float acc[WD];
#pragma unroll
  for (int k = 0; k < WD; ++k) acc[k] = 0.f;
  const float4* s4 = (const float4*)src;
  const float4* W4 = (const float4*)Wl;
  for (int c = 0; c < D / 4; ++c) {
    float4 xv = s4[c];
#pragma unroll
    for (int k = 0; k < WD; ++k) {
      float4 wv = W4[k * (D / 4) + c];
      acc[k] += xv.x * wv.x + xv.y * wv.y + xv.z * wv.z + xv.w * wv.w;
    }
  }
#pragma unroll
  for (int k = 0; k < WD; ++k) {
    float be = bias[k] * wscale[k] + wshift[k];
    dst[k] = acc[k] + be;
  }
}

// ---------------- K0: banded dist precompute, compact [b][d][a] ----------------
// slot m = t2-t1+81; par=(d+1)&1; m=2a+par; t1 = ((d+81-par)>>1) - a; t2 = d-t1.
__global__ __launch_bounds__(256) void dist_kernel(
    const float* __restrict__ xw, const float* __restrict__ yw,
    float* __restrict__ dc) {
  int b = blockIdx.y;
  int i = blockIdx.x * 256 + threadIdx.x;
  if (i >= NCELL) return;
  int d = (int)((unsigned)i / 81u);
  int a = i - d * 81;
  int par = (d + 1) & 1;
  int base = (d + 81 - par) >> 1;
  int t1 = base - a;
  int t2 = d - t1;
  if ((unsigned)t1 >= (unsigned)T || (unsigned)t2 >= (unsigned)T) return;
  const float4* xr = (const float4*)(xw + ((size_t)b * T + t1) * WD);
  const float4* yr = (const float4*)(yw + ((size_t)b * T + t2) * WD);
  float s = 0.f;
#pragma unroll
  for (int q = 0; q < 8; ++q) {
    float4 xv = xr[q], yv = yr[q];
    float d0 = xv.x - yv.x, d1 = xv.y - yv.y, d2 = xv.z - yv.z, d3 = xv.w - yv.w;
    s = fmaf(d0, d0, s); s = fmaf(d1, d1, s); s = fmaf(d2, d2, s); s = fmaf(d3, d3, s);
  }
  dc[((size_t)b * NSTEP + d) * 81 + a] = s;
}

// ---------------- K2: serial banded DP, 2 waves, 1 barrier/step ----------------
// Thread a owns slots {2a, 2a+1}. Own regs: v0 = slot 2a (par0), v1 = slot 2a+1 (par1).
// par=0 (d odd):  cell slot 2a:  up = v1 (own), left = vs[2a]   (thread a-1), diag = v0.
// par=1 (d even): cell slot 2a+1: left = v0 (own), up = vs[2a+3] (thread a+1), diag = v1.
// Writes: par0 -> vs[2a+1]; par1 -> vs[2a+2]. Read/write parities disjoint per step.
#define STEP(PREG, PAR, DVAL, PF_EN)                                       \
  {                                                                        \
    const int d_ = (DVAL);                                                 \
    const int base_ = (d_ + 81 - (PAR)) >> 1;                              \
    if (act) {                                                             \
      float lu = vs[(PAR) ? (2 * a + 3) : (2 * a)];                        \
      int t1 = base_ - a;                                                  \
      int t2 = d_ - t1;                                                    \
      bool valid = ((unsigned)t1 < (unsigned)T) && ((unsigned)t2 < (unsigned)T); \
      float distv = PREG;                                                  \
      if (PF_EN) PREG = dcb[(d_ + 8) * 81 + a];                            \
      if (valid) {                                                         \
        float up   = (PAR) ? lu : v1;                                      \
        float left = (PAR) ? v0 : lu;                                      \
        float diag = (PAR) ? v1 : v0;                                      \
        float cu = (t1 > 0) ? up : BIG;                                    \
        float cl = (t2 > 0) ? left : BIG;                                  \
        float cd = (t1 > 0 && t2 > 0) ? diag : BIG;                        \
        float mn = fminf(fminf(cu, cl), cd);                               \
        float mx = fmaxf(fmaxf(cu, cl), cd);                               \
        float md = fmaxf(fminf(cu, cl), fminf(fmaxf(cu, cl), cd));         \
        float ss = 1.f + __expf(mn - md) + __expf(mn - mx);                \
        float val = distv + mn - __logf(ss);                               \
        if (PAR) v1 = val; else v0 = val;                                  \
        vs[(PAR) ? (2 * a + 2) : (2 * a + 1)] = val;                       \
        outb[t1 * T + t2] = val;                                           \
      }                                                                    \
    }                                                                      \
    asm volatile("s_waitcnt lgkmcnt(0)" ::: "memory");                     \
    __builtin_amdgcn_s_barrier();                                          \
  }

__global__ __launch_bounds__(128) void dtw_kernel(
    const float* __restrict__ dc, float* __restrict__ path) {
  __shared__ float vs[164];
  int b = blockIdx.x;
  int a = threadIdx.x;
  for (int i = a; i < 164; i += 128) vs[i] = 0.f;
  __syncthreads();
  const float* dcb = dc + (size_t)b * NSTEP * 81;
  float* outb = path + (size_t)b * T * T;
  bool act = a < 81;
  float v0 = 0.f, v1 = 0.f;
  // d = 0: cell (0,0) is slot 81 = 2*40+1, par=1, handled specially (val = dist).
  if (a == 40) {
    float dist0 = dcb[40];
    v1 = dist0;
    vs[1 + 81] = dist0;
    outb[0] = dist0;
  }
  // prefetch steps d=1..8
  float p0 = 0.f, p1 = 0.f, p2 = 0.f, p3 = 0.f, p4 = 0.f, p5 = 0.f, p6 = 0.f, p7 = 0.f;
  if (act) {
    p0 = dcb[1 * 81 + a]; p1 = dcb[2 * 81 + a]; p2 = dcb[3 * 81 + a]; p3 = dcb[4 * 81 + a];
    p4 = dcb[5 * 81 + a]; p5 = dcb[6 * 81 + a]; p6 = dcb[7 * 81 + a]; p7 = dcb[8 * 81 + a];
  }
  asm volatile("s_waitcnt lgkmcnt(0)" ::: "memory");
  __builtin_amdgcn_s_barrier();
  // main: d = 1..632 (79 x 8), parity: d odd -> par 0 (k even since dbase odd)
  for (int dbase = 1; dbase <= 625; dbase += 8) {
    STEP(p0, 0, dbase + 0, 1)
    STEP(p1, 1, dbase + 1, 1)
    STEP(p2, 0, dbase + 2, 1)
    STEP(p3, 1, dbase + 3, 1)
    STEP(p4, 0, dbase + 4, 1)
    STEP(p5, 1, dbase + 5, 1)
    STEP(p6, 0, dbase + 6, 1)
    STEP(p7, 1, dbase + 7, 1)
  }
  // tail: d = 633..638 using p0..p5, no further prefetch
  STEP(p0, 0, 633, 0)
  STEP(p1, 1, 634, 0)
  STEP(p2, 0, 635, 0)
  STEP(p3, 1, 636, 0)
  STEP(p4, 0, 637, 0)
  STEP(p5, 1, 638, 0)
}

// ---------------- K3: row softmax of -val, band-masked read, in place ----------------
__global__ __launch_bounds__(T) void softmax_kernel(float* __restrict__ path) {
  __shared__ float sm1[5], sm2[5];
  int row = blockIdx.x;
  int t1 = row % T;
  int j = threadIdx.x;
  float* p = path + (size_t)row * T;
  bool in = (j >= t1 - 81) && (j <= t1 + 80);
  float v = in ? p[j] : 0.f;  // out-of-band cells are exact 0 in the reference
  float m = v;
#pragma unroll
  for (int off = 32; off >= 1; off >>= 1) m = fminf(m, __shfl_xor(m, off, 64));
  int w = j >> 6;
  if ((j & 63) == 0) sm1[w] = m;
  __syncthreads();
  m = fminf(fminf(fminf(sm1[0], sm1[1]), fminf(sm1[2], sm1[3])), sm1[4]);
  float e = __expf(m - v);  // exp(-v - max(-v))
  float s = e;
#pragma unroll
  for (int off = 32; off >= 1; off >>= 1) s += __shfl_xor(s, off, 64);
  if ((j & 63) == 0) sm2[w] = s;
  __syncthreads();
  s = sm2[0] + sm2[1] + sm2[2] + sm2[3] + sm2[4];
  p[j] = e / s;
}

// ---------------- K3b: column sums -> scale = 1/(colsum+1e-10) ----------------
__global__ __launch_bounds__(T) void colsum_kernel(
    const float* __restrict__ path, float* __restrict__ scale) {
  int b = blockIdx.x;
  int j = threadIdx.x;
  const float* p = path + (size_t)b * T * T;
  float s = 0.f;
  for (int t = 0; t < T; ++t) s += p[(size_t)t * T + j];
  scale[b * T + j] = 1.f / (s + 1e-10f);
}

// ---------------- K4: aligned[b,s,d] = scale[b,s] * sum_t P[b,t,s]*x[b,t,d] ----------------
#define TS 64
#define TDD 128
#define TK 16
__global__ __launch_bounds__(256) void bmm_kernel(
    const float* __restrict__ path, const float* __restrict__ x,
    const float* __restrict__ scale, float* __restrict__ out) {
  __shared__ __align__(16) float Pl[TK][TS];
  __shared__ __align__(16) float Xl[TK][TDD];
  int b = blockIdx.z;
  int s0 = blockIdx.y * TS;
  int d0 = blockIdx.x * TDD;
  int tid = threadIdx.x;
  int ts = tid & 15, td = tid >> 4;
  const float* pb = path + (size_t)b * T * T;
  const float* xb = x + (size_t)b * T * D;
  float acc[4][8];
#pragma unroll
  for (int i = 0; i < 4; ++i)
#pragma unroll
    for (int jj = 0; jj < 8; ++jj) acc[i][jj] = 0.f;
  for (int t0 = 0; t0 < T; t0 += TK) {
    __syncthreads();
    {
      int tr = tid >> 4;
      int sc = (tid & 15) * 4;
      *((float4*)&Pl[tr][sc]) = *((const float4*)&pb[(size_t)(t0 + tr) * T + s0 + sc]);
    }
    {
      int tr = tid >> 5;
      int dcq = (tid & 31) * 4;
      *((float4*)&Xl[tr][dcq]) = *((const float4*)&xb[(size_t)(t0 + tr) * D + d0 + dcq]);
      *((float4*)&Xl[tr + 8][dcq]) = *((const float4*)&xb[(size_t)(t0 + tr + 8) * D + d0 + dcq]);
    }
    __syncthreads();
#pragma unroll
    for (int t = 0; t < TK; ++t) {
      float4 pv = *((const float4*)&Pl[t][ts * 4]);
      float4 xa = *((const float4*)&Xl[t][td * 8]);
      float4 xc = *((const float4*)&Xl[t][td * 8 + 4]);
      float pvv[4] = {pv.x, pv.y, pv.z, pv.w};
      float xvv[8] = {xa.x, xa.y, xa.z, xa.w, xc.x, xc.y, xc.z, xc.w};
#pragma unroll
      for (int i = 0; i < 4; ++i)
#pragma unroll
        for (int jj = 0; jj < 8; ++jj) acc[i][jj] += pvv[i] * xvv[jj];
    }
  }
#pragma unroll
  for (int i = 0; i < 4; ++i) {
    int s = s0 + ts * 4 + i;
    float sc = scale[b * T + s];
    float4 o0, o1;
    o0.x = acc[i][0] * sc; o0.y = acc[i][1] * sc; o0.z = acc[i][2] * sc; o0.w = acc[i][3] * sc;
    o1.x = acc[i][4] * sc; o1.y = acc[i][5] * sc; o1.z = acc[i][6] * sc; o1.w = acc[i][7] * sc;
    float* op = out + ((size_t)b * T + s) * D + d0 + td * 8;
    *((float4*)op) = o0;
    *((float4*)(op + 4)) = o1;
  }
}

extern "C" void kernel_launch(void* const* d_in, const int* in_sizes, int n_in,
                              void* d_out, int out_size, void* d_ws, size_t ws_size,
                              hipStream_t stream) {
  const float* x = (const float*)d_in[0];
  const float* y = (const float*)d_in[1];
  const float* W = (const float*)d_in[2];
  const float* bias = (const float*)d_in[3];
  const float* wscale = (const float*)d_in[4];
  const float* wshift = (const float*)d_in[5];
  float* outp = (float*)d_out;
  float* aligned = outp;                          // [B,T,D] (written last by bmm)
  float* path = outp + (size_t)NB * T * D;        // [B,T,T]
  float* distc = aligned;                         // 13.3 MB scratch overlaid in aligned region
  float* ws = (float*)d_ws;
  float* xw = ws;
  float* yw = xw + (size_t)NB * T * WD;
  float* scale = yw + (size_t)NB * T * WD;        // [B,T]

  proj_kernel<<<dim3((2 * NB * T) / 256), 256, 0, stream>>>(x, y, W, bias, wscale, wshift, xw, yw);
  dist_kernel<<<dim3((NCELL + 255) / 256, NB), 256, 0, stream>>>(xw, yw, distc);
  dtw_kernel<<<dim3(NB), 128, 0, stream>>>(distc, path);
  softmax_kernel<<<dim3(NB * T), T, 0, stream>>>(path);
  colsum_kernel<<<dim3(NB), T, 0, stream>>>(path, scale);
  bmm_kernel<<<dim3(D / TDD, T / TS, NB), 256, 0, stream>>>(path, x, scale, aligned);
}

// Round 4
// 525.720 us; speedup vs baseline: 1.2609x; 1.0928x over previous
//
#include <hip/hip_runtime.h>

#define NB 64
#define T 320
#define D 768
#define WD 32
#define NSTEP 639
#define NCELL (NSTEP * 81)
#define BIG 1e30f

// ---------------- K1: projection  xw = x @ Weff^T + beff ----------------
__global__ __launch_bounds__(256) void proj_kernel(
    const float* __restrict__ x, const float* __restrict__ y,
    const float* __restrict__ W, const float* __restrict__ bias,
    const float* __restrict__ wscale, const float* __restrict__ wshift,
    float* __restrict__ xw, float* __restrict__ yw) {
  __shared__ __align__(16) float Wl[WD * D];
  int tid = threadIdx.x;
  for (int i = tid; i < WD * D; i += 256) {
    int k = i / D;
    Wl[i] = W[i] * wscale[k];
  }
  __syncthreads();
  int r = blockIdx.x * 256 + tid;
  const float* src;
  float* dst;
  if (r < NB * T) { src = x + (size_t)r * D; dst = xw + (size_t)r * WD; }
  else            { src = y + (size_t)(r - NB * T) * D; dst = yw + (size_t)(r - NB * T) * WD; }
  float acc[WD];
#pragma unroll
  for (int k = 0; k < WD; ++k) acc[k] = 0.f;
  const float4* s4 = (const float4*)src;
  const float4* W4 = (const float4*)Wl;
  for (int c = 0; c < D / 4; ++c) {
    float4 xv = s4[c];
#pragma unroll
    for (int k = 0; k < WD; ++k) {
      float4 wv = W4[k * (D / 4) + c];
      acc[k] += xv.x * wv.x + xv.y * wv.y + xv.z * wv.z + xv.w * wv.w;
    }
  }
#pragma unroll
  for (int k = 0; k < WD; ++k) {
    float be = bias[k] * wscale[k] + wshift[k];
    dst[k] = acc[k] + be;
  }
}

// ---------------- K0: banded dist precompute, compact [b][d][a] ----------------
// slot m = t2-t1+81; par=(d+1)&1; m=2a+par; t1 = ((d+81-par)>>1) - a; t2 = d-t1.
__global__ __launch_bounds__(256) void dist_kernel(
    const float* __restrict__ xw, const float* __restrict__ yw,
    float* __restrict__ dc) {
  int b = blockIdx.y;
  int i = blockIdx.x * 256 + threadIdx.x;
  if (i >= NCELL) return;
  int d = (int)((unsigned)i / 81u);
  int a = i - d * 81;
  int par = (d + 1) & 1;
  int base = (d + 81 - par) >> 1;
  int t1 = base - a;
  int t2 = d - t1;
  if ((unsigned)t1 >= (unsigned)T || (unsigned)t2 >= (unsigned)T) return;
  const float4* xr = (const float4*)(xw + ((size_t)b * T + t1) * WD);
  const float4* yr = (const float4*)(yw + ((size_t)b * T + t2) * WD);
  float s = 0.f;
#pragma unroll
  for (int q = 0; q < 8; ++q) {
    float4 xv = xr[q], yv = yr[q];
    float d0 = xv.x - yv.x, d1 = xv.y - yv.y, d2 = xv.z - yv.z, d3 = xv.w - yv.w;
    s = fmaf(d0, d0, s); s = fmaf(d1, d1, s); s = fmaf(d2, d2, s); s = fmaf(d3, d3, s);
  }
  dc[((size_t)b * NSTEP + d) * 81 + a] = s;
}

// ---------------- K2: single-wave banded DP, shfl neighbor exchange ----------------
// One wave per batch. Lane l owns slot-pair a=l (v0=slot 2l par0, v1=slot 2l+1 par1);
// lanes 0..16 also own a=l+64 (v0b=slot 128+2l, v1b=slot 129+2l).
// Per step exactly one value crosses lanes (slot +-1) -> one shfl per cell set.
// Out-of-band neighbors (slot -1, slot 162) read 0.0, matching reference storage.
#define STEP(PP, PS, PAR, DVAL, PF_EN)                                         \
  {                                                                            \
    const int d_ = (DVAL);                                                     \
    const int base_ = (d_ + 81 - (PAR)) >> 1;                                  \
    float shP, shS;                                                            \
    if (PAR) {                                                                 \
      shP = __shfl((l == 0) ? v0b : v0, (l + 1) & 63);                         \
      shS = __shfl(v0b, (l + 1) & 63);                                         \
    } else {                                                                   \
      shP = __shfl(v1, (l - 1) & 63);                                          \
      shS = __shfl((l == 63) ? v1 : v1b, (l - 1) & 63);                        \
    }                                                                          \
    int t1 = base_ - l, t2 = d_ - t1;                                          \
    int t1b = t1 - 64, t2b = d_ - t1b;                                         \
    float distP = PP, distS = PS;                                              \
    if (PF_EN) {                                                               \
      PP = dcb[(d_ + 8) * 81 + l];                                             \
      PS = dcb[(d_ + 8) * 81 + 64 + l];                                        \
    }                                                                          \
    { /* primary cell a = l */                                                 \
      bool valid = ((unsigned)t1 < (unsigned)T) && ((unsigned)t2 < (unsigned)T); \
      float up, left, diag;                                                    \
      if (PAR) { left = v0; up = shP; diag = v1; }                             \
      else     { up = v1; left = (l == 0) ? 0.f : shP; diag = v0; }            \
      float cu = (t1 > 0) ? up : BIG;                                          \
      float cl = (t2 > 0) ? left : BIG;                                        \
      float cd = (t1 > 0 && t2 > 0) ? diag : BIG;                              \
      float mn = fminf(fminf(cu, cl), cd);                                     \
      float mx = fmaxf(fmaxf(cu, cl), cd);                                     \
      float md = fmaxf(fminf(cu, cl), fminf(fmaxf(cu, cl), cd));               \
      float ss = 1.f + __expf(mn - md) + __expf(mn - mx);                      \
      float val = distP + mn - __logf(ss);                                     \
      if (valid) {                                                             \
        if (PAR) v1 = val; else v0 = val;                                      \
        outb[t1 * T + t2] = val;                                               \
      }                                                                        \
    }                                                                          \
    { /* secondary cell a = l + 64 (lanes 0..16) */                            \
      bool valid = (l < 17) && ((unsigned)t1b < (unsigned)T) &&                \
                   ((unsigned)t2b < (unsigned)T);                              \
      float up, left, diag;                                                    \
      if (PAR) { left = v0b; up = (l == 16) ? 0.f : shS; diag = v1b; }         \
      else     { up = v1b; left = shS; diag = v0b; }                           \
      float cu = (t1b > 0) ? up : BIG;                                         \
      float cl = (t2b > 0) ? left : BIG;                                       \
      float cd = (t1b > 0 && t2b > 0) ? diag : BIG;                            \
      float mn = fminf(fminf(cu, cl), cd);                                     \
      float mx = fmaxf(fmaxf(cu, cl), cd);                                     \
      float md = fmaxf(fminf(cu, cl), fminf(fmaxf(cu, cl), cd));               \
      float ss = 1.f + __expf(mn - md) + __expf(mn - mx);                      \
      float val = distS + mn - __logf(ss);                                     \
      if (valid) {                                                             \
        if (PAR) v1b = val; else v0b = val;                                    \
        outb[t1b * T + t2b] = val;                                             \
      }                                                                        \
    }                                                                          \
  }

__global__ __launch_bounds__(64) void dtw_kernel(
    const float* __restrict__ dc, float* __restrict__ path) {
  int b = blockIdx.x;
  int l = threadIdx.x;
  const float* dcb = dc + (size_t)b * NSTEP * 81;
  float* outb = path + (size_t)b * T * T;
  float v0 = 0.f, v1 = 0.f, v0b = 0.f, v1b = 0.f;
  // d = 0: cell (0,0) = slot 81 = pair a=40 par1 -> lane 40's v1. val = dist.
  if (l == 40) {
    float d00 = dcb[40];
    v1 = d00;
    outb[0] = d00;
  }
  // prefetch d = 1..8
  float pP0 = dcb[1 * 81 + l], pS0 = dcb[1 * 81 + 64 + l];
  float pP1 = dcb[2 * 81 + l], pS1 = dcb[2 * 81 + 64 + l];
  float pP2 = dcb[3 * 81 + l], pS2 = dcb[3 * 81 + 64 + l];
  float pP3 = dcb[4 * 81 + l], pS3 = dcb[4 * 81 + 64 + l];
  float pP4 = dcb[5 * 81 + l], pS4 = dcb[5 * 81 + 64 + l];
  float pP5 = dcb[6 * 81 + l], pS5 = dcb[6 * 81 + 64 + l];
  float pP6 = dcb[7 * 81 + l], pS6 = dcb[7 * 81 + 64 + l];
  float pP7 = dcb[8 * 81 + l], pS7 = dcb[8 * 81 + 64 + l];
  // main: d = 1..632 (79 x 8); d odd -> par 0
  for (int dbase = 1; dbase <= 625; dbase += 8) {
    STEP(pP0, pS0, 0, dbase + 0, 1)
    STEP(pP1, pS1, 1, dbase + 1, 1)
    STEP(pP2, pS2, 0, dbase + 2, 1)
    STEP(pP3, pS3, 1, dbase + 3, 1)
    STEP(pP4, pS4, 0, dbase + 4, 1)
    STEP(pP5, pS5, 1, dbase + 5, 1)
    STEP(pP6, pS6, 0, dbase + 6, 1)
    STEP(pP7, pS7, 1, dbase + 7, 1)
  }
  // tail: d = 633..638
  STEP(pP0, pS0, 0, 633, 0)
  STEP(pP1, pS1, 1, 634, 0)
  STEP(pP2, pS2, 0, 635, 0)
  STEP(pP3, pS3, 1, 636, 0)
  STEP(pP4, pS4, 0, 637, 0)
  STEP(pP5, pS5, 1, 638, 0)
}

// ---------------- K3: row softmax of -val, band-masked read, in place ----------------
__global__ __launch_bounds__(T) void softmax_kernel(float* __restrict__ path) {
  __shared__ float sm1[5], sm2[5];
  int row = blockIdx.x;
  int t1 = row % T;
  int j = threadIdx.x;
  float* p = path + (size_t)row * T;
  bool in = (j >= t1 - 81) && (j <= t1 + 80);
  float v = in ? p[j] : 0.f;  // out-of-band cells are exact 0 in the reference
  float m = v;
#pragma unroll
  for (int off = 32; off >= 1; off >>= 1) m = fminf(m, __shfl_xor(m, off, 64));
  int w = j >> 6;
  if ((j & 63) == 0) sm1[w] = m;
  __syncthreads();
  m = fminf(fminf(fminf(sm1[0], sm1[1]), fminf(sm1[2], sm1[3])), sm1[4]);
  float e = __expf(m - v);  // exp(-v - max(-v))
  float s = e;
#pragma unroll
  for (int off = 32; off >= 1; off >>= 1) s += __shfl_xor(s, off, 64);
  if ((j & 63) == 0) sm2[w] = s;
  __syncthreads();
  s = sm2[0] + sm2[1] + sm2[2] + sm2[3] + sm2[4];
  p[j] = e / s;
}

// ---------------- K3b: column sums -> scale = 1/(colsum+1e-10) ----------------
__global__ __launch_bounds__(T) void colsum_kernel(
    const float* __restrict__ path, float* __restrict__ scale) {
  int b = blockIdx.x;
  int j = threadIdx.x;
  const float* p = path + (size_t)b * T * T;
  float s = 0.f;
  for (int t = 0; t < T; ++t) s += p[(size_t)t * T + j];
  scale[b * T + j] = 1.f / (s + 1e-10f);
}

// ---------------- K4: aligned[b,s,d] = scale[b,s] * sum_t P[b,t,s]*x[b,t,d] ----------------
#define TS 64
#define TDD 128
#define TK 16
__global__ __launch_bounds__(256) void bmm_kernel(
    const float* __restrict__ path, const float* __restrict__ x,
    const float* __restrict__ scale, float* __restrict__ out) {
  __shared__ __align__(16) float Pl[TK][TS];
  __shared__ __align__(16) float Xl[TK][TDD];
  int b = blockIdx.z;
  int s0 = blockIdx.y * TS;
  int d0 = blockIdx.x * TDD;
  int tid = threadIdx.x;
  int ts = tid & 15, td = tid >> 4;
  const float* pb = path + (size_t)b * T * T;
  const float* xb = x + (size_t)b * T * D;
  float acc[4][8];
#pragma unroll
  for (int i = 0; i < 4; ++i)
#pragma unroll
    for (int jj = 0; jj < 8; ++jj) acc[i][jj] = 0.f;
  for (int t0 = 0; t0 < T; t0 += TK) {
    __syncthreads();
    {
      int tr = tid >> 4;
      int sc = (tid & 15) * 4;
      *((float4*)&Pl[tr][sc]) = *((const float4*)&pb[(size_t)(t0 + tr) * T + s0 + sc]);
    }
    {
      int tr = tid >> 5;
      int dcq = (tid & 31) * 4;
      *((float4*)&Xl[tr][dcq]) = *((const float4*)&xb[(size_t)(t0 + tr) * D + d0 + dcq]);
      *((float4*)&Xl[tr + 8][dcq]) = *((const float4*)&xb[(size_t)(t0 + tr + 8) * D + d0 + dcq]);
    }
    __syncthreads();
#pragma unroll
    for (int t = 0; t < TK; ++t) {
      float4 pv = *((const float4*)&Pl[t][ts * 4]);
      float4 xa = *((const float4*)&Xl[t][td * 8]);
      float4 xc = *((const float4*)&Xl[t][td * 8 + 4]);
      float pvv[4] = {pv.x, pv.y, pv.z, pv.w};
      float xvv[8] = {xa.x, xa.y, xa.z, xa.w, xc.x, xc.y, xc.z, xc.w};
#pragma unroll
      for (int i = 0; i < 4; ++i)
#pragma unroll
        for (int jj = 0; jj < 8; ++jj) acc[i][jj] += pvv[i] * xvv[jj];
    }
  }
#pragma unroll
  for (int i = 0; i < 4; ++i) {
    int s = s0 + ts * 4 + i;
    float sc = scale[b * T + s];
    float4 o0, o1;
    o0.x = acc[i][0] * sc; o0.y = acc[i][1] * sc; o0.z = acc[i][2] * sc; o0.w = acc[i][3] * sc;
    o1.x = acc[i][4] * sc; o1.y = acc[i][5] * sc; o1.z = acc[i][6] * sc; o1.w = acc[i][7] * sc;
    float* op = out + ((size_t)b * T + s) * D + d0 + td * 8;
    *((float4*)op) = o0;
    *((float4*)(op + 4)) = o1;
  }
}

extern "C" void kernel_launch(void* const* d_in, const int* in_sizes, int n_in,
                              void* d_out, int out_size, void* d_ws, size_t ws_size,
                              hipStream_t stream) {
  const float* x = (const float*)d_in[0];
  const float* y = (const float*)d_in[1];
  const float* W = (const float*)d_in[2];
  const float* bias = (const float*)d_in[3];
  const float* wscale = (const float*)d_in[4];
  const float* wshift = (const float*)d_in[5];
  float* outp = (float*)d_out;
  float* aligned = outp;                          // [B,T,D] (written last by bmm)
  float* path = outp + (size_t)NB * T * D;        // [B,T,T]
  float* distc = aligned;                         // 13.3 MB scratch overlaid in aligned region
  float* ws = (float*)d_ws;
  float* xw = ws;
  float* yw = xw + (size_t)NB * T * WD;
  float* scale = yw + (size_t)NB * T * WD;        // [B,T]

  proj_kernel<<<dim3((2 * NB * T) / 256), 256, 0, stream>>>(x, y, W, bias, wscale, wshift, xw, yw);
  dist_kernel<<<dim3((NCELL + 255) / 256, NB), 256, 0, stream>>>(xw, yw, distc);
  dtw_kernel<<<dim3(NB), 64, 0, stream>>>(distc, path);
  softmax_kernel<<<dim3(NB * T), T, 0, stream>>>(path);
  colsum_kernel<<<dim3(NB), T, 0, stream>>>(path, scale);
  bmm_kernel<<<dim3(D / TDD, T / TS, NB), 256, 0, stream>>>(path, x, scale, aligned);
}

// Round 5
// 496.405 us; speedup vs baseline: 1.3353x; 1.0591x over previous
//
#include <hip/hip_runtime.h>

#define NB 64
#define T 320
#define D 768
#define WD 32
#define NSTEP 639
#define NBLK 80
#define BSTRIDE (NBLK * 1024)
#define BIG 1e30f

// ---------------- K1: projection  xw = x @ Weff^T + beff ----------------
__global__ __launch_bounds__(256) void proj_kernel(
    const float* __restrict__ x, const float* __restrict__ y,
    const float* __restrict__ W, const float* __restrict__ bias,
    const float* __restrict__ wscale, const float* __restrict__ wshift,
    float* __restrict__ xw, float* __restrict__ yw) {
  __shared__ __align__(16) float Wl[WD * D];
  int tid = threadIdx.x;
  for (int i = tid; i < WD * D; i += 256) {
    int k = i / D;
    Wl[i] = W[i] * wscale[k];
  }
  __syncthreads();
  int r = blockIdx.x * 256 + tid;
  const float* src;
  float* dst;
  if (r < NB * T) { src = x + (size_t)r * D; dst = xw + (size_t)r * WD; }
  else            { src = y + (size_t)(r - NB * T) * D; dst = yw + (size_t)(r - NB * T) * WD; }
  float acc[WD];
#pragma unroll
  for (int k = 0; k < WD; ++k) acc[k] = 0.f;
  const float4* s4 = (const float4*)src;
  const float4* W4 = (const float4*)Wl;
  for (int c = 0; c < D / 4; ++c) {
    float4 xv = s4[c];
#pragma unroll
    for (int k = 0; k < WD; ++k) {
      float4 wv = W4[k * (D / 4) + c];
      acc[k] += xv.x * wv.x + xv.y * wv.y + xv.z * wv.z + xv.w * wv.w;
    }
  }
#pragma unroll
  for (int k = 0; k < WD; ++k) {
    float be = bias[k] * wscale[k] + wshift[k];
    dst[k] = acc[k] + be;
  }
}

// ---------------- K0: banded dist precompute, layout [b][dblk][a][8] ----------------
// d = dblk*8 + k; slot m = t2-t1+81; par=(d+1)&1; m=2a+par; t1=((d+81-par)>>1)-a.
// Lane-l DP streams read a=l (primary) and a=64+l (secondary) as 2x float4 per block.
__global__ __launch_bounds__(256) void dist_kernel(
    const float* __restrict__ xw, const float* __restrict__ yw,
    float* __restrict__ dc) {
  int b = blockIdx.y;
  int i = blockIdx.x * 256 + threadIdx.x;  // i = dblk*1024 + a*8 + k
  int dblk = i >> 10;
  int a = (i >> 3) & 127;
  int k = i & 7;
  if (a >= 81) return;
  int d = dblk * 8 + k;
  if (d >= NSTEP) return;
  int par = (d + 1) & 1;
  int base = (d + 81 - par) >> 1;
  int t1 = base - a;
  int t2 = d - t1;
  if ((unsigned)t1 >= (unsigned)T || (unsigned)t2 >= (unsigned)T) return;
  const float4* xr = (const float4*)(xw + ((size_t)b * T + t1) * WD);
  const float4* yr = (const float4*)(yw + ((size_t)b * T + t2) * WD);
  float s = 0.f;
#pragma unroll
  for (int q = 0; q < 8; ++q) {
    float4 xv = xr[q], yv = yr[q];
    float d0 = xv.x - yv.x, d1 = xv.y - yv.y, d2 = xv.z - yv.z, d3 = xv.w - yv.w;
    s = fmaf(d0, d0, s); s = fmaf(d1, d1, s); s = fmaf(d2, d2, s); s = fmaf(d3, d3, s);
  }
  dc[(size_t)b * BSTRIDE + i] = s;
}

// ---------------- K2: single-wave banded DP ----------------
// Lane l owns slot-pair a=l (v0=slot 2l, v1=slot 2l+1); lanes 0..16 also a=l+64
// (v0b,v1b). One value crosses lanes per step -> one shfl per stream.
// Steady regime d in [96,527]: all band cells grid-valid, t1>0 & t2>0
// (t1max = base(543)=312<320; t1bmin = base(96)-80 = 8>0; t2min = (96-81+1)/2 = 8;
//  t2bmax = (527-81+1)/2+80+16 < 320) -> no gates, incremental store offsets.

// Full-checked step (prologue/epilogue). DP_/DS_ are dist values (by value).
#define FSTEP(DP_, DS_, PAR, DVAL)                                             \
  {                                                                            \
    const int d_ = (DVAL);                                                     \
    const int base_ = (d_ + 81 - (PAR)) >> 1;                                  \
    float shP, shS;                                                            \
    if (PAR) {                                                                 \
      shP = __shfl((l == 0) ? v0b : v0, lp1);                                  \
      shS = __shfl(v0b, lp1);                                                  \
    } else {                                                                   \
      shP = __shfl(v1, lm1);                                                   \
      shS = __shfl((l == 63) ? v1 : v1b, lm1);                                 \
    }                                                                          \
    int t1 = base_ - l, t2 = d_ - t1;                                          \
    { /* primary cell a=l */                                                   \
      bool valid = ((unsigned)t1 < (unsigned)T) && ((unsigned)t2 < (unsigned)T); \
      float up, left, diag;                                                    \
      if (PAR) { left = v0; up = shP; diag = v1; }                             \
      else     { up = v1; left = (l == 0) ? 0.f : shP; diag = v0; }            \
      float cu = (t1 > 0) ? up : BIG;                                          \
      float cl = (t2 > 0) ? left : BIG;                                        \
      float cd = (t1 > 0 && t2 > 0) ? diag : BIG;                              \
      float mn = fminf(fminf(cu, cl), cd);                                     \
      float mx = fmaxf(fmaxf(cu, cl), cd);                                     \
      float md = fmaxf(fminf(cu, cl), fminf(fmaxf(cu, cl), cd));               \
      float ss = 1.f + __expf(mn - md) + __expf(mn - mx);                      \
      float val = (DP_) + mn - __logf(ss);                                     \
      if ((DVAL) == 0) val = (DP_); /* cell (0,0): no softmin */               \
      if (valid) {                                                             \
        if (PAR) v1 = val; else v0 = val;                                      \
        outb[t1 * T + t2] = val;                                               \
      }                                                                        \
    }                                                                          \
    { /* secondary cell a=l+64 (lanes 0..16) */                                \
      int t1b = t1 - 64, t2b = t2 + 64;                                        \
      bool valid = (l < 17) && ((unsigned)t1b < (unsigned)T) &&                \
                   ((unsigned)t2b < (unsigned)T);                              \
      float up, left, diag;                                                    \
      if (PAR) { left = v0b; up = (l == 16) ? 0.f : shS; diag = v1b; }         \
      else     { up = v1b; left = shS; diag = v0b; }                           \
      float cu = (t1b > 0) ? up : BIG;                                         \
      float cl = (t2b > 0) ? left : BIG;                                       \
      float cd = (t1b > 0 && t2b > 0) ? diag : BIG;                            \
      float mn = fminf(fminf(cu, cl), cd);                                     \
      float mx = fmaxf(fmaxf(cu, cl), cd);                                     \
      float md = fmaxf(fminf(cu, cl), fminf(fmaxf(cu, cl), cd));               \
      float ss = 1.f + __expf(mn - md) + __expf(mn - mx);                      \
      float val = (DS_) + mn - __logf(ss);                                     \
      if (valid) {                                                             \
        if (PAR) v1b = val; else v0b = val;                                    \
        outb[t1b * T + t2b] = val;                                             \
      }                                                                        \
    }                                                                          \
  }

// Steady step: no gates, no validity, imm-offset stores off incremental io/ioS.
// Lanes 17..63 compute garbage secondaries (never consumed: par1 up is muxed to 0
// at l==16; par0 shS reads only lanes 63,0..15), stores exec-masked by l<17.
#define SSTEP(DP_, DS_, PAR, IOFF)                                             \
  {                                                                            \
    float shP, shS;                                                            \
    if (PAR) {                                                                 \
      shP = __shfl((l == 0) ? v0b : v0, lp1);                                  \
      shS = __shfl(v0b, lp1);                                                  \
    } else {                                                                   \
      shP = __shfl(v1, lm1);                                                   \
      shS = __shfl((l == 63) ? v1 : v1b, lm1);                                 \
    }                                                                          \
    {                                                                          \
      float up, left, diag;                                                    \
      if (PAR) { left = v0; up = shP; diag = v1; }                             \
      else     { up = v1; left = (l == 0) ? 0.f : shP; diag = v0; }            \
      float mn = fminf(fminf(up, left), diag);                                 \
      float mx = fmaxf(fmaxf(up, left), diag);                                 \
      float md = fmaxf(fminf(up, left), fminf(fmaxf(up, left), diag));         \
      float ss = 1.f + __expf(mn - md) + __expf(mn - mx);                      \
      float val = (DP_) + mn - __logf(ss);                                     \
      if (PAR) v1 = val; else v0 = val;                                        \
      outb[io + (IOFF)] = val;                                                 \
    }                                                                          \
    {                                                                          \
      float up, left, diag;                                                    \
      if (PAR) { left = v0b; up = (l == 16) ? 0.f : shS; diag = v1b; }         \
      else     { up = v1b; left = shS; diag = v0b; }                           \
      float mn = fminf(fminf(up, left), diag);                                 \
      float mx = fmaxf(fmaxf(up, left), diag);                                 \
      float md = fmaxf(fminf(up, left), fminf(fmaxf(up, left), diag));         \
      float ss = 1.f + __expf(mn - md) + __expf(mn - mx);                      \
      float val = (DS_) + mn - __logf(ss);                                     \
      if (PAR) v1b = val; else v0b = val;                                      \
      if (l < 17) outb[ioS + (IOFF)] = val;                                    \
    }                                                                          \
  }

#define LOADBLK(R0, R1, S0v, S1v, DBLK)                                        \
  {                                                                            \
    const float4* q_ = (const float4*)(dcb + (DBLK) * 1024 + l * 8);           \
    R0 = q_[0]; R1 = q_[1];                                                    \
    const float4* q2_ = (const float4*)(dcb + (DBLK) * 1024 + (64 + l) * 8);   \
    S0v = q2_[0]; S1v = q2_[1];                                                \
  }

// 8 full-checked steps, even DB -> par1 first
#define BLK8_F(P0, P1, S0v, S1v, DB)                                           \
  FSTEP(P0.x, S0v.x, 1, (DB) + 0) FSTEP(P0.y, S0v.y, 0, (DB) + 1)              \
  FSTEP(P0.z, S0v.z, 1, (DB) + 2) FSTEP(P0.w, S0v.w, 0, (DB) + 3)              \
  FSTEP(P1.x, S1v.x, 1, (DB) + 4) FSTEP(P1.y, S1v.y, 0, (DB) + 5)              \
  FSTEP(P1.z, S1v.z, 1, (DB) + 6) FSTEP(P1.w, S1v.w, 0, (DB) + 7)

// 8 steady steps (par1 first); io/ioS advance every 4 steps (keeps imm offsets small)
#define BLK8_S(P0, P1, S0v, S1v)                                               \
  SSTEP(P0.x, S0v.x, 1, 0)   SSTEP(P0.y, S0v.y, 0, 320)                        \
  SSTEP(P0.z, S0v.z, 1, 321) SSTEP(P0.w, S0v.w, 0, 641)                        \
  io += 642; ioS += 642;                                                       \
  SSTEP(P1.x, S1v.x, 1, 0)   SSTEP(P1.y, S1v.y, 0, 320)                        \
  SSTEP(P1.z, S1v.z, 1, 321) SSTEP(P1.w, S1v.w, 0, 641)                        \
  io += 642; ioS += 642;

__global__ __launch_bounds__(64) void dtw_kernel(
    const float* __restrict__ dc, float* __restrict__ path) {
  int b = blockIdx.x;
  int l = threadIdx.x;
  const float* dcb = dc + (size_t)b * BSTRIDE;
  float* outb = path + (size_t)b * T * T;
  int lp1 = (l + 1) & 63, lm1 = (l - 1) & 63;
  float v0 = 0.f, v1 = 0.f, v0b = 0.f, v1b = 0.f;
  float4 aP0, aP1, aS0, aS1, bP0, bP1, bS0, bS1;
  int io = 0, ioS = 0;  // used only in steady regime

  LOADBLK(aP0, aP1, aS0, aS1, 0)
  // prologue d = 0..95 (full checks; d==0 override inside FSTEP)
#pragma clang loop unroll(disable)
  for (int it = 0; it < 6; ++it) {
    int dbase = it * 16;
    int blk = it * 2;
    LOADBLK(bP0, bP1, bS0, bS1, blk + 1)
    BLK8_F(aP0, aP1, aS0, aS1, dbase)
    LOADBLK(aP0, aP1, aS0, aS1, blk + 2)
    BLK8_F(bP0, bP1, bS0, bS1, dbase + 8)
  }
  // steady d = 96..527: d=96 par1, t1=88-l, t2=8+l
  io = 28168 - 319 * l;
  ioS = io - 20416;
#pragma clang loop unroll(disable)
  for (int it = 0; it < 27; ++it) {
    int blk = 12 + it * 2;
    LOADBLK(bP0, bP1, bS0, bS1, blk + 1)
    BLK8_S(aP0, aP1, aS0, aS1)
    LOADBLK(aP0, aP1, aS0, aS1, blk + 2)
    BLK8_S(bP0, bP1, bS0, bS1)
  }
  // epilogue d = 528..623 (full checks)
#pragma clang loop unroll(disable)
  for (int it = 0; it < 6; ++it) {
    int dbase = 528 + it * 16;
    int blk = 66 + it * 2;
    LOADBLK(bP0, bP1, bS0, bS1, blk + 1)
    BLK8_F(aP0, aP1, aS0, aS1, dbase)
    LOADBLK(aP0, aP1, aS0, aS1, blk + 2)
    BLK8_F(bP0, bP1, bS0, bS1, dbase + 8)
  }
  // final block d = 624..631, then tail 632..638
  LOADBLK(bP0, bP1, bS0, bS1, 79)
  BLK8_F(aP0, aP1, aS0, aS1, 624)
  FSTEP(bP0.x, bS0.x, 1, 632) FSTEP(bP0.y, bS0.y, 0, 633)
  FSTEP(bP0.z, bS0.z, 1, 634) FSTEP(bP0.w, bS0.w, 0, 635)
  FSTEP(bP1.x, bS1.x, 1, 636) FSTEP(bP1.y, bS1.y, 0, 637)
  FSTEP(bP1.z, bS1.z, 1, 638)
}

// ---------------- K3: row softmax of -val, band-masked read, in place ----------------
__global__ __launch_bounds__(T) void softmax_kernel(float* __restrict__ path) {
  __shared__ float sm1[5], sm2[5];
  int row = blockIdx.x;
  int t1 = row % T;
  int j = threadIdx.x;
  float* p = path + (size_t)row * T;
  bool in = (j >= t1 - 81) && (j <= t1 + 80);
  float v = in ? p[j] : 0.f;  // out-of-band cells are exact 0 in the reference
  float m = v;
#pragma unroll
  for (int off = 32; off >= 1; off >>= 1) m = fminf(m, __shfl_xor(m, off, 64));
  int w = j >> 6;
  if ((j & 63) == 0) sm1[w] = m;
  __syncthreads();
  m = fminf(fminf(fminf(sm1[0], sm1[1]), fminf(sm1[2], sm1[3])), sm1[4]);
  float e = __expf(m - v);  // exp(-v - max(-v))
  float s = e;
#pragma unroll
  for (int off = 32; off >= 1; off >>= 1) s += __shfl_xor(s, off, 64);
  if ((j & 63) == 0) sm2[w] = s;
  __syncthreads();
  s = sm2[0] + sm2[1] + sm2[2] + sm2[3] + sm2[4];
  p[j] = e / s;
}

// ---------------- K3b: column sums -> scale = 1/(colsum+1e-10) ----------------
__global__ __launch_bounds__(T) void colsum_kernel(
    const float* __restrict__ path, float* __restrict__ scale) {
  int b = blockIdx.x;
  int j = threadIdx.x;
  const float* p = path + (size_t)b * T * T;
  float s = 0.f;
  for (int t = 0; t < T; ++t) s += p[(size_t)t * T + j];
  scale[b * T + j] = 1.f / (s + 1e-10f);
}

// ---------------- K4: aligned[b,s,d] = scale[b,s] * sum_t P[b,t,s]*x[b,t,d] ----------------
#define TS 64
#define TDD 128
#define TK 16
__global__ __launch_bounds__(256) void bmm_kernel(
    const float* __restrict__ path, const float* __restrict__ x,
    const float* __restrict__ scale, float* __restrict__ out) {
  __shared__ __align__(16) float Pl[TK][TS];
  __shared__ __align__(16) float Xl[TK][TDD];
  int b = blockIdx.z;
  int s0 = blockIdx.y * TS;
  int d0 = blockIdx.x * TDD;
  int tid = threadIdx.x;
  int ts = tid & 15, td = tid >> 4;
  const float* pb = path + (size_t)b * T * T;
  const float* xb = x + (size_t)b * T * D;
  float acc[4][8];
#pragma unroll
  for (int i = 0; i < 4; ++i)
#pragma unroll
    for (int jj = 0; jj < 8; ++jj) acc[i][jj] = 0.f;
  for (int t0 = 0; t0 < T; t0 += TK) {
    __syncthreads();
    {
      int tr = tid >> 4;
      int sc = (tid & 15) * 4;
      *((float4*)&Pl[tr][sc]) = *((const float4*)&pb[(size_t)(t0 + tr) * T + s0 + sc]);
    }
    {
      int tr = tid >> 5;
      int dcq = (tid & 31) * 4;
      *((float4*)&Xl[tr][dcq]) = *((const float4*)&xb[(size_t)(t0 + tr) * D + d0 + dcq]);
      *((float4*)&Xl[tr + 8][dcq]) = *((const float4*)&xb[(size_t)(t0 + tr + 8) * D + d0 + dcq]);
    }
    __syncthreads();
#pragma unroll
    for (int t = 0; t < TK; ++t) {
      float4 pv = *((const float4*)&Pl[t][ts * 4]);
      float4 xa = *((const float4*)&Xl[t][td * 8]);
      float4 xc = *((const float4*)&Xl[t][td * 8 + 4]);
      float pvv[4] = {pv.x, pv.y, pv.z, pv.w};
      float xvv[8] = {xa.x, xa.y, xa.z, xa.w, xc.x, xc.y, xc.z, xc.w};
#pragma unroll
      for (int i = 0; i < 4; ++i)
#pragma unroll
        for (int jj = 0; jj < 8; ++jj) acc[i][jj] += pvv[i] * xvv[jj];
    }
  }
#pragma unroll
  for (int i = 0; i < 4; ++i) {
    int s = s0 + ts * 4 + i;
    float sc = scale[b * T + s];
    float4 o0, o1;
    o0.x = acc[i][0] * sc; o0.y = acc[i][1] * sc; o0.z = acc[i][2] * sc; o0.w = acc[i][3] * sc;
    o1.x = acc[i][4] * sc; o1.y = acc[i][5] * sc; o1.z = acc[i][6] * sc; o1.w = acc[i][7] * sc;
    float* op = out + ((size_t)b * T + s) * D + d0 + td * 8;
    *((float4*)op) = o0;
    *((float4*)(op + 4)) = o1;
  }
}

extern "C" void kernel_launch(void* const* d_in, const int* in_sizes, int n_in,
                              void* d_out, int out_size, void* d_ws, size_t ws_size,
                              hipStream_t stream) {
  const float* x = (const float*)d_in[0];
  const float* y = (const float*)d_in[1];
  const float* W = (const float*)d_in[2];
  const float* bias = (const float*)d_in[3];
  const float* wscale = (const float*)d_in[4];
  const float* wshift = (const float*)d_in[5];
  float* outp = (float*)d_out;
  float* aligned = outp;                          // [B,T,D] (written last by bmm)
  float* path = outp + (size_t)NB * T * D;        // [B,T,T]
  float* distc = aligned;                         // 21 MB scratch overlaid in aligned region
  float* ws = (float*)d_ws;
  float* xw = ws;
  float* yw = xw + (size_t)NB * T * WD;
  float* scale = yw + (size_t)NB * T * WD;        // [B,T]

  proj_kernel<<<dim3((2 * NB * T) / 256), 256, 0, stream>>>(x, y, W, bias, wscale, wshift, xw, yw);
  dist_kernel<<<dim3(BSTRIDE / 256, NB), 256, 0, stream>>>(xw, yw, distc);
  dtw_kernel<<<dim3(NB), 64, 0, stream>>>(distc, path);
  softmax_kernel<<<dim3(NB * T), T, 0, stream>>>(path);
  colsum_kernel<<<dim3(NB), T, 0, stream>>>(path, scale);
  bmm_kernel<<<dim3(D / TDD, T / TS, NB), 256, 0, stream>>>(path, x, scale, aligned);
}

// Round 6
// 484.422 us; speedup vs baseline: 1.3684x; 1.0247x over previous
//
#include <hip/hip_runtime.h>

#define NB 64
#define T 320
#define D 768
#define WD 32
#define NSTEP 639
#define NBLK 80
#define BSTRIDE (NBLK * 1024)
#define BIG 1e30f

// ---------------- K_prep: WeT[c][k] = W[k][c]*wscale[k];  beff[k] ----------------
__global__ __launch_bounds__(256) void prep_kernel(
    const float* __restrict__ W, const float* __restrict__ bias,
    const float* __restrict__ wscale, const float* __restrict__ wshift,
    float* __restrict__ WeT, float* __restrict__ beff) {
  int i = blockIdx.x * 256 + threadIdx.x;  // i = c*32 + k
  int c = i >> 5, k = i & 31;
  WeT[i] = W[k * D + c] * wscale[k];
  if (i < WD) beff[i] = bias[i] * wscale[i] + wshift[i];
}

// ---------------- K1: projection, W via wave-uniform scalar loads ----------------
__global__ __launch_bounds__(64) void proj_kernel(
    const float* __restrict__ x, const float* __restrict__ y,
    const float* __restrict__ WeT, const float* __restrict__ beff,
    float* __restrict__ xw, float* __restrict__ yw) {
  int r = blockIdx.x * 64 + threadIdx.x;
  const float* src;
  float* dst;
  if (r < NB * T) { src = x + (size_t)r * D; dst = xw + (size_t)r * WD; }
  else            { src = y + (size_t)(r - NB * T) * D; dst = yw + (size_t)(r - NB * T) * WD; }
  float acc[WD];
#pragma unroll
  for (int k = 0; k < WD; ++k) acc[k] = 0.f;
  const float4* s4 = (const float4*)src;
  for (int c4 = 0; c4 < D / 4; ++c4) {
    float4 xv = s4[c4];
    const float* wr = WeT + c4 * 128;  // 4 columns x 32 k, consecutive, wave-uniform
#pragma unroll
    for (int cc = 0; cc < 4; ++cc) {
      float xs = (cc == 0) ? xv.x : (cc == 1) ? xv.y : (cc == 2) ? xv.z : xv.w;
#pragma unroll
      for (int k = 0; k < WD; ++k)
        acc[k] = fmaf(wr[cc * 32 + k], xs, acc[k]);
    }
  }
#pragma unroll
  for (int k = 0; k < WD; ++k) dst[k] = acc[k] + beff[k];
}

// ---------------- K0: banded dist precompute, layout [b][dblk][a][8] ----------------
__global__ __launch_bounds__(256) void dist_kernel(
    const float* __restrict__ xw, const float* __restrict__ yw,
    float* __restrict__ dc) {
  int b = blockIdx.y;
  int i = blockIdx.x * 256 + threadIdx.x;  // i = dblk*1024 + a*8 + k
  int dblk = i >> 10;
  int a = (i >> 3) & 127;
  int k = i & 7;
  if (a >= 81) return;
  int d = dblk * 8 + k;
  if (d >= NSTEP) return;
  int par = (d + 1) & 1;
  int base = (d + 81 - par) >> 1;
  int t1 = base - a;
  int t2 = d - t1;
  if ((unsigned)t1 >= (unsigned)T || (unsigned)t2 >= (unsigned)T) return;
  const float4* xr = (const float4*)(xw + ((size_t)b * T + t1) * WD);
  const float4* yr = (const float4*)(yw + ((size_t)b * T + t2) * WD);
  float s = 0.f;
#pragma unroll
  for (int q = 0; q < 8; ++q) {
    float4 xv = xr[q], yv = yr[q];
    float d0 = xv.x - yv.x, d1 = xv.y - yv.y, d2 = xv.z - yv.z, d3 = xv.w - yv.w;
    s = fmaf(d0, d0, s); s = fmaf(d1, d1, s); s = fmaf(d2, d2, s); s = fmaf(d3, d3, s);
  }
  dc[(size_t)b * BSTRIDE + i] = s;
}

// ---------------- K2: single-wave banded DP (unchanged from round 5) ----------------
#define FSTEP(DP_, DS_, PAR, DVAL)                                             \
  {                                                                            \
    const int d_ = (DVAL);                                                     \
    const int base_ = (d_ + 81 - (PAR)) >> 1;                                  \
    float shP, shS;                                                            \
    if (PAR) {                                                                 \
      shP = __shfl((l == 0) ? v0b : v0, lp1);                                  \
      shS = __shfl(v0b, lp1);                                                  \
    } else {                                                                   \
      shP = __shfl(v1, lm1);                                                   \
      shS = __shfl((l == 63) ? v1 : v1b, lm1);                                 \
    }                                                                          \
    int t1 = base_ - l, t2 = d_ - t1;                                          \
    {                                                                          \
      bool valid = ((unsigned)t1 < (unsigned)T) && ((unsigned)t2 < (unsigned)T); \
      float up, left, diag;                                                    \
      if (PAR) { left = v0; up = shP; diag = v1; }                             \
      else     { up = v1; left = (l == 0) ? 0.f : shP; diag = v0; }            \
      float cu = (t1 > 0) ? up : BIG;                                          \
      float cl = (t2 > 0) ? left : BIG;                                        \
      float cd = (t1 > 0 && t2 > 0) ? diag : BIG;                              \
      float mn = fminf(fminf(cu, cl), cd);                                     \
      float mx = fmaxf(fmaxf(cu, cl), cd);                                     \
      float md = fmaxf(fminf(cu, cl), fminf(fmaxf(cu, cl), cd));               \
      float ss = 1.f + __expf(mn - md) + __expf(mn - mx);                      \
      float val = (DP_) + mn - __logf(ss);                                     \
      if ((DVAL) == 0) val = (DP_);                                            \
      if (valid) {                                                             \
        if (PAR) v1 = val; else v0 = val;                                      \
        outb[t1 * T + t2] = val;                                               \
      }                                                                        \
    }                                                                          \
    {                                                                          \
      int t1b = t1 - 64, t2b = t2 + 64;                                        \
      bool valid = (l < 17) && ((unsigned)t1b < (unsigned)T) &&                \
                   ((unsigned)t2b < (unsigned)T);                              \
      float up, left, diag;                                                    \
      if (PAR) { left = v0b; up = (l == 16) ? 0.f : shS; diag = v1b; }         \
      else     { up = v1b; left = shS; diag = v0b; }                           \
      float cu = (t1b > 0) ? up : BIG;                                         \
      float cl = (t2b > 0) ? left : BIG;                                       \
      float cd = (t1b > 0 && t2b > 0) ? diag : BIG;                            \
      float mn = fminf(fminf(cu, cl), cd);                                     \
      float mx = fmaxf(fmaxf(cu, cl), cd);                                     \
      float md = fmaxf(fminf(cu, cl), fminf(fmaxf(cu, cl), cd));               \
      float ss = 1.f + __expf(mn - md) + __expf(mn - mx);                      \
      float val = (DS_) + mn - __logf(ss);                                     \
      if (valid) {                                                             \
        if (PAR) v1b = val; else v0b = val;                                    \
        outb[t1b * T + t2b] = val;                                             \
      }                                                                        \
    }                                                                          \
  }

#define SSTEP(DP_, DS_, PAR, IOFF)                                             \
  {                                                                            \
    float shP, shS;                                                            \
    if (PAR) {                                                                 \
      shP = __shfl((l == 0) ? v0b : v0, lp1);                                  \
      shS = __shfl(v0b, lp1);                                                  \
    } else {                                                                   \
      shP = __shfl(v1, lm1);                                                   \
      shS = __shfl((l == 63) ? v1 : v1b, lm1);                                 \
    }                                                                          \
    {                                                                          \
      float up, left, diag;                                                    \
      if (PAR) { left = v0; up = shP; diag = v1; }                             \
      else     { up = v1; left = (l == 0) ? 0.f : shP; diag = v0; }            \
      float mn = fminf(fminf(up, left), diag);                                 \
      float mx = fmaxf(fmaxf(up, left), diag);                                 \
      float md = fmaxf(fminf(up, left), fminf(fmaxf(up, left), diag));         \
      float ss = 1.f + __expf(mn - md) + __expf(mn - mx);                      \
      float val = (DP_) + mn - __logf(ss);                                     \
      if (PAR) v1 = val; else v0 = val;                                        \
      outb[io + (IOFF)] = val;                                                 \
    }                                                                          \
    {                                                                          \
      float up, left, diag;                                                    \
      if (PAR) { left = v0b; up = (l == 16) ? 0.f : shS; diag = v1b; }         \
      else     { up = v1b; left = shS; diag = v0b; }                           \
      float mn = fminf(fminf(up, left), diag);                                 \
      float mx = fmaxf(fmaxf(up, left), diag);                                 \
      float md = fmaxf(fminf(up, left), fminf(fmaxf(up, left), diag));         \
      float ss = 1.f + __expf(mn - md) + __expf(mn - mx);                      \
      float val = (DS_) + mn - __logf(ss);                                     \
      if (PAR) v1b = val; else v0b = val;                                      \
      if (l < 17) outb[ioS + (IOFF)] = val;                                    \
    }                                                                          \
  }

#define LOADBLK(R0, R1, S0v, S1v, DBLK)                                        \
  {                                                                            \
    const float4* q_ = (const float4*)(dcb + (DBLK) * 1024 + l * 8);           \
    R0 = q_[0]; R1 = q_[1];                                                    \
    const float4* q2_ = (const float4*)(dcb + (DBLK) * 1024 + (64 + l) * 8);   \
    S0v = q2_[0]; S1v = q2_[1];                                                \
  }

#define BLK8_F(P0, P1, S0v, S1v, DB)                                           \
  FSTEP(P0.x, S0v.x, 1, (DB) + 0) FSTEP(P0.y, S0v.y, 0, (DB) + 1)              \
  FSTEP(P0.z, S0v.z, 1, (DB) + 2) FSTEP(P0.w, S0v.w, 0, (DB) + 3)              \
  FSTEP(P1.x, S1v.x, 1, (DB) + 4) FSTEP(P1.y, S1v.y, 0, (DB) + 5)              \
  FSTEP(P1.z, S1v.z, 1, (DB) + 6) FSTEP(P1.w, S1v.w, 0, (DB) + 7)

#define BLK8_S(P0, P1, S0v, S1v)                                               \
  SSTEP(P0.x, S0v.x, 1, 0)   SSTEP(P0.y, S0v.y, 0, 320)                        \
  SSTEP(P0.z, S0v.z, 1, 321) SSTEP(P0.w, S0v.w, 0, 641)                        \
  io += 642; ioS += 642;                                                       \
  SSTEP(P1.x, S1v.x, 1, 0)   SSTEP(P1.y, S1v.y, 0, 320)                        \
  SSTEP(P1.z, S1v.z, 1, 321) SSTEP(P1.w, S1v.w, 0, 641)                        \
  io += 642; ioS += 642;

__global__ __launch_bounds__(64) void dtw_kernel(
    const float* __restrict__ dc, float* __restrict__ path) {
  int b = blockIdx.x;
  int l = threadIdx.x;
  const float* dcb = dc + (size_t)b * BSTRIDE;
  float* outb = path + (size_t)b * T * T;
  int lp1 = (l + 1) & 63, lm1 = (l - 1) & 63;
  float v0 = 0.f, v1 = 0.f, v0b = 0.f, v1b = 0.f;
  float4 aP0, aP1, aS0, aS1, bP0, bP1, bS0, bS1;
  int io = 0, ioS = 0;

  LOADBLK(aP0, aP1, aS0, aS1, 0)
#pragma clang loop unroll(disable)
  for (int it = 0; it < 6; ++it) {
    int dbase = it * 16;
    int blk = it * 2;
    LOADBLK(bP0, bP1, bS0, bS1, blk + 1)
    BLK8_F(aP0, aP1, aS0, aS1, dbase)
    LOADBLK(aP0, aP1, aS0, aS1, blk + 2)
    BLK8_F(bP0, bP1, bS0, bS1, dbase + 8)
  }
  io = 28168 - 319 * l;
  ioS = io - 20416;
#pragma clang loop unroll(disable)
  for (int it = 0; it < 27; ++it) {
    int blk = 12 + it * 2;
    LOADBLK(bP0, bP1, bS0, bS1, blk + 1)
    BLK8_S(aP0, aP1, aS0, aS1)
    LOADBLK(aP0, aP1, aS0, aS1, blk + 2)
    BLK8_S(bP0, bP1, bS0, bS1)
  }
#pragma clang loop unroll(disable)
  for (int it = 0; it < 6; ++it) {
    int dbase = 528 + it * 16;
    int blk = 66 + it * 2;
    LOADBLK(bP0, bP1, bS0, bS1, blk + 1)
    BLK8_F(aP0, aP1, aS0, aS1, dbase)
    LOADBLK(aP0, aP1, aS0, aS1, blk + 2)
    BLK8_F(bP0, bP1, bS0, bS1, dbase + 8)
  }
  LOADBLK(bP0, bP1, bS0, bS1, 79)
  BLK8_F(aP0, aP1, aS0, aS1, 624)
  FSTEP(bP0.x, bS0.x, 1, 632) FSTEP(bP0.y, bS0.y, 0, 633)
  FSTEP(bP0.z, bS0.z, 1, 634) FSTEP(bP0.w, bS0.w, 0, 635)
  FSTEP(bP1.x, bS1.x, 1, 636) FSTEP(bP1.y, bS1.y, 0, 637)
  FSTEP(bP1.z, bS1.z, 1, 638)
}

// ---------------- K3: row softmax (in place) + cvec = exp(m)/S (out-of-band prob) ----------------
__global__ __launch_bounds__(T) void softmax_kernel(float* __restrict__ path,
                                                    float* __restrict__ cvec) {
  __shared__ float sm1[5], sm2[5];
  int row = blockIdx.x;
  int t1 = row % T;
  int j = threadIdx.x;
  float* p = path + (size_t)row * T;
  bool in = (j >= t1 - 81) && (j <= t1 + 80);
  float v = in ? p[j] : 0.f;  // out-of-band cells are exact 0 in the reference
  float m = v;
#pragma unroll
  for (int off = 32; off >= 1; off >>= 1) m = fminf(m, __shfl_xor(m, off, 64));
  int w = j >> 6;
  if ((j & 63) == 0) sm1[w] = m;
  __syncthreads();
  m = fminf(fminf(fminf(sm1[0], sm1[1]), fminf(sm1[2], sm1[3])), sm1[4]);
  float e = __expf(m - v);
  float s = e;
#pragma unroll
  for (int off = 32; off >= 1; off >>= 1) s += __shfl_xor(s, off, 64);
  if ((j & 63) == 0) sm2[w] = s;
  __syncthreads();
  s = sm2[0] + sm2[1] + sm2[2] + sm2[3] + sm2[4];
  p[j] = e / s;
  if (j == 0) cvec[row] = __expf(m - 0.f) / s;  // bitwise == out-of-band p[j]
}

// ---------------- K3g: g[b][d] = sum_t cvec[b,t] * x[b,t,d] ----------------
__global__ __launch_bounds__(256) void gk_kernel(
    const float* __restrict__ x, const float* __restrict__ cvec,
    float* __restrict__ g) {
  int b = blockIdx.y;
  int d0 = blockIdx.x * 256 + threadIdx.x;
  const float* xb = x + (size_t)b * T * D + d0;
  const float* cb = cvec + b * T;  // wave-uniform reads
  float s = 0.f;
  for (int t = 0; t < T; ++t) s = fmaf(cb[t], xb[(size_t)t * D], s);
  g[b * D + d0] = s;
}

// ---------------- K3b: column sums -> scale = 1/(colsum+1e-10) (full column) ----------------
__global__ __launch_bounds__(T) void colsum_kernel(
    const float* __restrict__ path, float* __restrict__ scale) {
  int b = blockIdx.x;
  int j = threadIdx.x;
  const float* p = path + (size_t)b * T * T;
  float s = 0.f;
  for (int t = 0; t < T; ++t) s += p[(size_t)t * T + j];
  scale[b * T + j] = 1.f / (s + 1e-10f);
}

// ---------------- K4: aligned[b,s,d] = scale_s * (g[d] + sum_{t in band} P'[t,s]*x[t,d]) ----------------
// P'[t,s] = P[t,s] - cvec[t]  (exactly 0 out-of-band) -> t-loop restricted to band window.
#define TSB 64
#define TDB 256
#define TKB 16
__global__ __launch_bounds__(256) void bmm_kernel(
    const float* __restrict__ path, const float* __restrict__ x,
    const float* __restrict__ cvec, const float* __restrict__ g,
    const float* __restrict__ scale, float* __restrict__ out) {
  __shared__ __align__(16) float Pl[TKB][TSB];
  __shared__ __align__(16) float Xl[TKB][TDB];
  int b = blockIdx.z;
  int s0 = blockIdx.y * TSB;
  int d0 = blockIdx.x * TDB;
  int tid = threadIdx.x;
  int ts = tid & 7, td = tid >> 3;  // 8 s-groups x 32 d-groups, 8x8 per thread
  const float* pb = path + (size_t)b * T * T;
  const float* xb = x + (size_t)b * T * D;
  const float* cb = cvec + b * T;
  float acc[8][8];
  {
    const float* gb = g + b * D + d0 + td * 8;
    float4 g0 = *(const float4*)gb;
    float4 g1 = *(const float4*)(gb + 4);
    float gv[8] = {g0.x, g0.y, g0.z, g0.w, g1.x, g1.y, g1.z, g1.w};
#pragma unroll
    for (int i = 0; i < 8; ++i)
#pragma unroll
      for (int jj = 0; jj < 8; ++jj) acc[i][jj] = gv[jj];
  }
  int t_lo = s0 - 80; if (t_lo < 0) t_lo = 0; t_lo &= ~15;
  int t_hi = (s0 + 160) & ~15; if (t_hi > T) t_hi = T;
  for (int t0 = t_lo; t0 < t_hi; t0 += TKB) {
    __syncthreads();
    {  // stage P' = P - c_t : 16 x 64
      int tr = tid >> 4, sc = (tid & 15) * 4;
      float4 p4 = *(const float4*)&pb[(size_t)(t0 + tr) * T + s0 + sc];
      float cv = cb[t0 + tr];
      p4.x -= cv; p4.y -= cv; p4.z -= cv; p4.w -= cv;
      *(float4*)&Pl[tr][sc] = p4;
    }
    {  // stage X: 16 x 256
      int tr = tid >> 4, c0 = (tid & 15) * 4;
#pragma unroll
      for (int q = 0; q < 4; ++q)
        *(float4*)&Xl[tr][c0 + q * 64] =
            *(const float4*)&xb[(size_t)(t0 + tr) * D + d0 + c0 + q * 64];
    }
    __syncthreads();
#pragma unroll
    for (int t = 0; t < TKB; ++t) {
      float4 pa = *(const float4*)&Pl[t][ts * 8];
      float4 pc = *(const float4*)&Pl[t][ts * 8 + 4];
      float4 xa = *(const float4*)&Xl[t][td * 8];
      float4 xc = *(const float4*)&Xl[t][td * 8 + 4];
      float pv[8] = {pa.x, pa.y, pa.z, pa.w, pc.x, pc.y, pc.z, pc.w};
      float xv[8] = {xa.x, xa.y, xa.z, xa.w, xc.x, xc.y, xc.z, xc.w};
#pragma unroll
      for (int i = 0; i < 8; ++i)
#pragma unroll
        for (int jj = 0; jj < 8; ++jj)
          acc[i][jj] = fmaf(pv[i], xv[jj], acc[i][jj]);
    }
  }
#pragma unroll
  for (int i = 0; i < 8; ++i) {
    int s = s0 + ts * 8 + i;
    float sc = scale[b * T + s];
    float* op = out + ((size_t)b * T + s) * D + d0 + td * 8;
    float4 o0, o1;
    o0.x = acc[i][0] * sc; o0.y = acc[i][1] * sc; o0.z = acc[i][2] * sc; o0.w = acc[i][3] * sc;
    o1.x = acc[i][4] * sc; o1.y = acc[i][5] * sc; o1.z = acc[i][6] * sc; o1.w = acc[i][7] * sc;
    *(float4*)op = o0;
    *(float4*)(op + 4) = o1;
  }
}

extern "C" void kernel_launch(void* const* d_in, const int* in_sizes, int n_in,
                              void* d_out, int out_size, void* d_ws, size_t ws_size,
                              hipStream_t stream) {
  const float* x = (const float*)d_in[0];
  const float* y = (const float*)d_in[1];
  const float* W = (const float*)d_in[2];
  const float* bias = (const float*)d_in[3];
  const float* wscale = (const float*)d_in[4];
  const float* wshift = (const float*)d_in[5];
  float* outp = (float*)d_out;
  float* aligned = outp;                          // [B,T,D] (written last by bmm)
  float* path = outp + (size_t)NB * T * D;        // [B,T,T]
  float* distc = aligned;                         // 21 MB scratch overlaid in aligned region
  float* ws = (float*)d_ws;
  float* xw = ws;                                 // 655360
  float* yw = xw + (size_t)NB * T * WD;           // 655360
  float* scale = yw + (size_t)NB * T * WD;        // 20480
  float* WeT = scale + (size_t)NB * T;            // 24576
  float* beff = WeT + (size_t)WD * D;             // 32
  float* cvec = beff + WD;                        // 20480
  float* g = cvec + (size_t)NB * T;               // 49152

  prep_kernel<<<dim3((WD * D) / 256), 256, 0, stream>>>(W, bias, wscale, wshift, WeT, beff);
  proj_kernel<<<dim3((2 * NB * T) / 64), 64, 0, stream>>>(x, y, WeT, beff, xw, yw);
  dist_kernel<<<dim3(BSTRIDE / 256, NB), 256, 0, stream>>>(xw, yw, distc);
  dtw_kernel<<<dim3(NB), 64, 0, stream>>>(distc, path);
  softmax_kernel<<<dim3(NB * T), T, 0, stream>>>(path, cvec);
  gk_kernel<<<dim3(D / 256, NB), 256, 0, stream>>>(x, cvec, g);
  colsum_kernel<<<dim3(NB), T, 0, stream>>>(path, scale);
  bmm_kernel<<<dim3(D / TDB, T / TSB, NB), 256, 0, stream>>>(path, x, cvec, g, scale, aligned);
}

// Round 7
// 438.750 us; speedup vs baseline: 1.5108x; 1.1041x over previous
//
#include <hip/hip_runtime.h>

#define NB 64
#define T 320
#define D 768
#define WD 32
#define NSTEP 639
#define NBLK 80
#define BSTRIDE (NBLK * 1024)
#define BIG 1e30f
#define LOG2E 1.44269504088896340736f
#define LN2 0.69314718055994530942f

// DPP lane rotations (VALU, no LDS pipe): ror1 = lane l <- lane (l-1)&63,
// rol1 = lane l <- lane (l+1)&63. gfx9-lineage wave_ror:1/wave_rol:1.
__device__ __forceinline__ float dpp_ror1(float v) {
  return __int_as_float(__builtin_amdgcn_update_dpp(
      0, __float_as_int(v), 0x13C, 0xF, 0xF, true));
}
__device__ __forceinline__ float dpp_rol1(float v) {
  return __int_as_float(__builtin_amdgcn_update_dpp(
      0, __float_as_int(v), 0x134, 0xF, 0xF, true));
}

// ---------------- K_prep: WeT[c][k] = W[k][c]*wscale[k];  beff[k] ----------------
__global__ __launch_bounds__(256) void prep_kernel(
    const float* __restrict__ W, const float* __restrict__ bias,
    const float* __restrict__ wscale, const float* __restrict__ wshift,
    float* __restrict__ WeT, float* __restrict__ beff) {
  int i = blockIdx.x * 256 + threadIdx.x;  // i = c*32 + k
  int c = i >> 5, k = i & 31;
  WeT[i] = W[k * D + c] * wscale[k];
  if (i < WD) beff[i] = bias[i] * wscale[i] + wshift[i];
}

// ---------------- K1: projection, W via wave-uniform scalar loads ----------------
__global__ __launch_bounds__(64) void proj_kernel(
    const float* __restrict__ x, const float* __restrict__ y,
    const float* __restrict__ WeT, const float* __restrict__ beff,
    float* __restrict__ xw, float* __restrict__ yw) {
  int r = blockIdx.x * 64 + threadIdx.x;
  const float* src;
  float* dst;
  if (r < NB * T) { src = x + (size_t)r * D; dst = xw + (size_t)r * WD; }
  else            { src = y + (size_t)(r - NB * T) * D; dst = yw + (size_t)(r - NB * T) * WD; }
  float acc[WD];
#pragma unroll
  for (int k = 0; k < WD; ++k) acc[k] = 0.f;
  const float4* s4 = (const float4*)src;
  for (int c4 = 0; c4 < D / 4; ++c4) {
    float4 xv = s4[c4];
    const float* wr = WeT + c4 * 128;  // wave-uniform -> s_load
#pragma unroll
    for (int cc = 0; cc < 4; ++cc) {
      float xs = (cc == 0) ? xv.x : (cc == 1) ? xv.y : (cc == 2) ? xv.z : xv.w;
#pragma unroll
      for (int k = 0; k < WD; ++k)
        acc[k] = fmaf(wr[cc * 32 + k], xs, acc[k]);
    }
  }
#pragma unroll
  for (int k = 0; k < WD; ++k) dst[k] = acc[k] + beff[k];
}

// ---------------- K0: banded dist precompute, layout [b][dblk][a][8], scaled by log2e ----------------
__global__ __launch_bounds__(256) void dist_kernel(
    const float* __restrict__ xw, const float* __restrict__ yw,
    float* __restrict__ dc) {
  int b = blockIdx.y;
  int i = blockIdx.x * 256 + threadIdx.x;  // i = dblk*1024 + a*8 + k
  int dblk = i >> 10;
  int a = (i >> 3) & 127;
  int k = i & 7;
  if (a >= 81) return;
  int d = dblk * 8 + k;
  if (d >= NSTEP) return;
  int par = (d + 1) & 1;
  int base = (d + 81 - par) >> 1;
  int t1 = base - a;
  int t2 = d - t1;
  if ((unsigned)t1 >= (unsigned)T || (unsigned)t2 >= (unsigned)T) return;
  const float4* xr = (const float4*)(xw + ((size_t)b * T + t1) * WD);
  const float4* yr = (const float4*)(yw + ((size_t)b * T + t2) * WD);
  float s = 0.f;
#pragma unroll
  for (int q = 0; q < 8; ++q) {
    float4 xv = xr[q], yv = yr[q];
    float d0 = xv.x - yv.x, d1 = xv.y - yv.y, d2 = xv.z - yv.z, d3 = xv.w - yv.w;
    s = fmaf(d0, d0, s); s = fmaf(d1, d1, s); s = fmaf(d2, d2, s); s = fmaf(d3, d3, s);
  }
  dc[(size_t)b * BSTRIDE + i] = s * LOG2E;  // base-2 scaled
}

// ---------------- K2: single-wave banded DP, DPP neighbor exchange, base-2 softmin ----------------
// Lane l owns slot-pair a=l (v0=slot 2l, v1=slot 2l+1); lanes 0..16 also a=l+64
// (v0b,v1b). DP state kept in log2e-scaled units; stores unscale by ln2.
#define FSTEP(DP_, DS_, PAR, DVAL)                                             \
  {                                                                            \
    const int d_ = (DVAL);                                                     \
    const int base_ = (d_ + 81 - (PAR)) >> 1;                                  \
    float shP, shS;                                                            \
    if (PAR) { shP = dpp_rol1((l == 0) ? v0b : v0); shS = dpp_rol1(v0b); }     \
    else     { shP = dpp_ror1(v1); shS = dpp_ror1((l == 63) ? v1 : v1b); }     \
    int t1 = base_ - l, t2 = d_ - t1;                                          \
    {                                                                          \
      bool valid = ((unsigned)t1 < (unsigned)T) && ((unsigned)t2 < (unsigned)T); \
      float up, left, diag;                                                    \
      if (PAR) { left = v0; up = shP; diag = v1; }                             \
      else     { up = v1; left = (l == 0) ? 0.f : shP; diag = v0; }            \
      float cu = (t1 > 0) ? up : BIG;                                          \
      float cl = (t2 > 0) ? left : BIG;                                        \
      float cd = (t1 > 0 && t2 > 0) ? diag : BIG;                              \
      float mn = fminf(fminf(cu, cl), cd);                                     \
      float mx = fmaxf(fmaxf(cu, cl), cd);                                     \
      float md = fmaxf(fminf(cu, cl), fminf(fmaxf(cu, cl), cd));               \
      float ss = 1.f + __builtin_amdgcn_exp2f(mn - md) +                       \
                 __builtin_amdgcn_exp2f(mn - mx);                              \
      float val = (DP_) + mn - __builtin_amdgcn_logf(ss);                      \
      if ((DVAL) == 0) val = (DP_);                                            \
      if (valid) {                                                             \
        if (PAR) v1 = val; else v0 = val;                                      \
        outb[t1 * T + t2] = val * LN2;                                         \
      }                                                                        \
    }                                                                          \
    {                                                                          \
      int t1b = t1 - 64, t2b = t2 + 64;                                        \
      bool valid = (l < 17) && ((unsigned)t1b < (unsigned)T) &&                \
                   ((unsigned)t2b < (unsigned)T);                              \
      float up, left, diag;                                                    \
      if (PAR) { left = v0b; up = (l == 16) ? 0.f : shS; diag = v1b; }         \
      else     { up = v1b; left = shS; diag = v0b; }                           \
      float cu = (t1b > 0) ? up : BIG;                                         \
      float cl = (t2b > 0) ? left : BIG;                                       \
      float cd = (t1b > 0 && t2b > 0) ? diag : BIG;                            \
      float mn = fminf(fminf(cu, cl), cd);                                     \
      float mx = fmaxf(fmaxf(cu, cl), cd);                                     \
      float md = fmaxf(fminf(cu, cl), fminf(fmaxf(cu, cl), cd));               \
      float ss = 1.f + __builtin_amdgcn_exp2f(mn - md) +                       \
                 __builtin_amdgcn_exp2f(mn - mx);                              \
      float val = (DS_) + mn - __builtin_amdgcn_logf(ss);                      \
      if (valid) {                                                             \
        if (PAR) v1b = val; else v0b = val;                                    \
        outb[t1b * T + t2b] = val * LN2;                                       \
      }                                                                        \
    }                                                                          \
  }

#define SSTEP(DP_, DS_, PAR, IOFF)                                             \
  {                                                                            \
    float shP, shS;                                                            \
    if (PAR) { shP = dpp_rol1((l == 0) ? v0b : v0); shS = dpp_rol1(v0b); }     \
    else     { shP = dpp_ror1(v1); shS = dpp_ror1((l == 63) ? v1 : v1b); }     \
    {                                                                          \
      float up, left, diag;                                                    \
      if (PAR) { left = v0; up = shP; diag = v1; }                             \
      else     { up = v1; left = (l == 0) ? 0.f : shP; diag = v0; }            \
      float mn = fminf(fminf(up, left), diag);                                 \
      float mx = fmaxf(fmaxf(up, left), diag);                                 \
      float md = fmaxf(fminf(up, left), fminf(fmaxf(up, left), diag));         \
      float ss = 1.f + __builtin_amdgcn_exp2f(mn - md) +                       \
                 __builtin_amdgcn_exp2f(mn - mx);                              \
      float val = (DP_) + mn - __builtin_amdgcn_logf(ss);                      \
      if (PAR) v1 = val; else v0 = val;                                        \
      outb[io + (IOFF)] = val * LN2;                                           \
    }                                                                          \
    {                                                                          \
      float up, left, diag;                                                    \
      if (PAR) { left = v0b; up = (l == 16) ? 0.f : shS; diag = v1b; }         \
      else     { up = v1b; left = shS; diag = v0b; }                           \
      float mn = fminf(fminf(up, left), diag);                                 \
      float mx = fmaxf(fmaxf(up, left), diag);                                 \
      float md = fmaxf(fminf(up, left), fminf(fmaxf(up, left), diag));         \
      float ss = 1.f + __builtin_amdgcn_exp2f(mn - md) +                       \
                 __builtin_amdgcn_exp2f(mn - mx);                              \
      float val = (DS_) + mn - __builtin_amdgcn_logf(ss);                      \
      if (PAR) v1b = val; else v0b = val;                                      \
      if (l < 17) outb[ioS + (IOFF)] = val * LN2;                              \
    }                                                                          \
  }

#define LOADBLK(R0, R1, S0v, S1v, DBLK)                                        \
  {                                                                            \
    const float4* q_ = (const float4*)(dcb + (DBLK) * 1024 + l * 8);           \
    R0 = q_[0]; R1 = q_[1];                                                    \
    const float4* q2_ = (const float4*)(dcb + (DBLK) * 1024 + (64 + l) * 8);   \
    S0v = q2_[0]; S1v = q2_[1];                                                \
  }

#define BLK8_F(P0, P1, S0v, S1v, DB)                                           \
  FSTEP(P0.x, S0v.x, 1, (DB) + 0) FSTEP(P0.y, S0v.y, 0, (DB) + 1)              \
  FSTEP(P0.z, S0v.z, 1, (DB) + 2) FSTEP(P0.w, S0v.w, 0, (DB) + 3)              \
  FSTEP(P1.x, S1v.x, 1, (DB) + 4) FSTEP(P1.y, S1v.y, 0, (DB) + 5)              \
  FSTEP(P1.z, S1v.z, 1, (DB) + 6) FSTEP(P1.w, S1v.w, 0, (DB) + 7)

#define BLK8_S(P0, P1, S0v, S1v)                                               \
  SSTEP(P0.x, S0v.x, 1, 0)   SSTEP(P0.y, S0v.y, 0, 320)                        \
  SSTEP(P0.z, S0v.z, 1, 321) SSTEP(P0.w, S0v.w, 0, 641)                        \
  io += 642; ioS += 642;                                                       \
  SSTEP(P1.x, S1v.x, 1, 0)   SSTEP(P1.y, S1v.y, 0, 320)                        \
  SSTEP(P1.z, S1v.z, 1, 321) SSTEP(P1.w, S1v.w, 0, 641)                        \
  io += 642; ioS += 642;

__global__ __launch_bounds__(64) void dtw_kernel(
    const float* __restrict__ dc, float* __restrict__ path) {
  int b = blockIdx.x;
  int l = threadIdx.x;
  const float* dcb = dc + (size_t)b * BSTRIDE;
  float* outb = path + (size_t)b * T * T;
  float v0 = 0.f, v1 = 0.f, v0b = 0.f, v1b = 0.f;
  float4 aP0, aP1, aS0, aS1, bP0, bP1, bS0, bS1;
  int io = 0, ioS = 0;

  // d = 0: cell (0,0) = slot 81 = pair a=40 par1. Layout index: a*8+k = 320.
  if (l == 40) {
    float d00 = dcb[320];
    v1 = d00;
    outb[0] = d00 * LN2;
  }
  LOADBLK(aP0, aP1, aS0, aS1, 0)
#pragma clang loop unroll(disable)
  for (int it = 0; it < 6; ++it) {
    int dbase = it * 16;
    int blk = it * 2;
    LOADBLK(bP0, bP1, bS0, bS1, blk + 1)
    BLK8_F(aP0, aP1, aS0, aS1, dbase)
    LOADBLK(aP0, aP1, aS0, aS1, blk + 2)
    BLK8_F(bP0, bP1, bS0, bS1, dbase + 8)
  }
  io = 28168 - 319 * l;
  ioS = io - 20416;
#pragma clang loop unroll(disable)
  for (int it = 0; it < 27; ++it) {
    int blk = 12 + it * 2;
    LOADBLK(bP0, bP1, bS0, bS1, blk + 1)
    BLK8_S(aP0, aP1, aS0, aS1)
    LOADBLK(aP0, aP1, aS0, aS1, blk + 2)
    BLK8_S(bP0, bP1, bS0, bS1)
  }
#pragma clang loop unroll(disable)
  for (int it = 0; it < 6; ++it) {
    int dbase = 528 + it * 16;
    int blk = 66 + it * 2;
    LOADBLK(bP0, bP1, bS0, bS1, blk + 1)
    BLK8_F(aP0, aP1, aS0, aS1, dbase)
    LOADBLK(aP0, aP1, aS0, aS1, blk + 2)
    BLK8_F(bP0, bP1, bS0, bS1, dbase + 8)
  }
  LOADBLK(bP0, bP1, bS0, bS1, 79)
  BLK8_F(aP0, aP1, aS0, aS1, 624)
  FSTEP(bP0.x, bS0.x, 1, 632) FSTEP(bP0.y, bS0.y, 0, 633)
  FSTEP(bP0.z, bS0.z, 1, 634) FSTEP(bP0.w, bS0.w, 0, 635)
  FSTEP(bP1.x, bS1.x, 1, 636) FSTEP(bP1.y, bS1.y, 0, 637)
  FSTEP(bP1.z, bS1.z, 1, 638)
}

// ---------------- K3: row softmax (in place) + cvec = exp(m)/S (out-of-band prob) ----------------
__global__ __launch_bounds__(T) void softmax_kernel(float* __restrict__ path,
                                                    float* __restrict__ cvec) {
  __shared__ float sm1[5], sm2[5];
  int row = blockIdx.x;
  int t1 = row % T;
  int j = threadIdx.x;
  float* p = path + (size_t)row * T;
  bool in = (j >= t1 - 81) && (j <= t1 + 80);
  float v = in ? p[j] : 0.f;  // out-of-band cells are exact 0 in the reference
  float m = v;
#pragma unroll
  for (int off = 32; off >= 1; off >>= 1) m = fminf(m, __shfl_xor(m, off, 64));
  int w = j >> 6;
  if ((j & 63) == 0) sm1[w] = m;
  __syncthreads();
  m = fminf(fminf(fminf(sm1[0], sm1[1]), fminf(sm1[2], sm1[3])), sm1[4]);
  float e = __expf(m - v);
  float s = e;
#pragma unroll
  for (int off = 32; off >= 1; off >>= 1) s += __shfl_xor(s, off, 64);
  if ((j & 63) == 0) sm2[w] = s;
  __syncthreads();
  s = sm2[0] + sm2[1] + sm2[2] + sm2[3] + sm2[4];
  p[j] = e / s;
  if (j == 0) cvec[row] = __expf(m - 0.f) / s;  // bitwise == out-of-band p[j]
}

// ---------------- K3g: g[b][d] = sum_t cvec[b,t] * x[b,t,d] ----------------
__global__ __launch_bounds__(256) void gk_kernel(
    const float* __restrict__ x, const float* __restrict__ cvec,
    float* __restrict__ g) {
  int b = blockIdx.y;
  int d0 = blockIdx.x * 256 + threadIdx.x;
  const float* xb = x + (size_t)b * T * D + d0;
  const float* cb = cvec + b * T;  // wave-uniform reads
  float s = 0.f;
  for (int t = 0; t < T; ++t) s = fmaf(cb[t], xb[(size_t)t * D], s);
  g[b * D + d0] = s;
}

// ---------------- K3b: column sums -> scale = 1/(colsum+1e-10) ----------------
__global__ __launch_bounds__(T) void colsum_kernel(
    const float* __restrict__ path, float* __restrict__ scale) {
  int b = blockIdx.x;
  int j = threadIdx.x;
  const float* p = path + (size_t)b * T * T;
  float s = 0.f;
  for (int t = 0; t < T; ++t) s += p[(size_t)t * T + j];
  scale[b * T + j] = 1.f / (s + 1e-10f);
}

// ---------------- K4: aligned[b,s,d] = scale_s * (g[d] + sum_{t in band} P'[t,s]*x[t,d]) ----------------
#define TSB 64
#define TDB 256
#define TKB 16
__global__ __launch_bounds__(256) void bmm_kernel(
    const float* __restrict__ path, const float* __restrict__ x,
    const float* __restrict__ cvec, const float* __restrict__ g,
    const float* __restrict__ scale, float* __restrict__ out) {
  __shared__ __align__(16) float Pl[TKB][TSB];
  __shared__ __align__(16) float Xl[TKB][TDB];
  int b = blockIdx.z;
  int s0 = blockIdx.y * TSB;
  int d0 = blockIdx.x * TDB;
  int tid = threadIdx.x;
  int ts = tid & 7, td = tid >> 3;
  const float* pb = path + (size_t)b * T * T;
  const float* xb = x + (size_t)b * T * D;
  const float* cb = cvec + b * T;
  float acc[8][8];
  {
    const float* gb = g + b * D + d0 + td * 8;
    float4 g0 = *(const float4*)gb;
    float4 g1 = *(const float4*)(gb + 4);
    float gv[8] = {g0.x, g0.y, g0.z, g0.w, g1.x, g1.y, g1.z, g1.w};
#pragma unroll
    for (int i = 0; i < 8; ++i)
#pragma unroll
      for (int jj = 0; jj < 8; ++jj) acc[i][jj] = gv[jj];
  }
  int t_lo = s0 - 80; if (t_lo < 0) t_lo = 0; t_lo &= ~15;
  int t_hi = (s0 + 160) & ~15; if (t_hi > T) t_hi = T;
  for (int t0 = t_lo; t0 < t_hi; t0 += TKB) {
    __syncthreads();
    {
      int tr = tid >> 4, sc = (tid & 15) * 4;
      float4 p4 = *(const float4*)&pb[(size_t)(t0 + tr) * T + s0 + sc];
      float cv = cb[t0 + tr];
      p4.x -= cv; p4.y -= cv; p4.z -= cv; p4.w -= cv;
      *(float4*)&Pl[tr][sc] = p4;
    }
    {
      int tr = tid >> 4, c0 = (tid & 15) * 4;
#pragma unroll
      for (int q = 0; q < 4; ++q)
        *(float4*)&Xl[tr][c0 + q * 64] =
            *(const float4*)&xb[(size_t)(t0 + tr) * D + d0 + c0 + q * 64];
    }
    __syncthreads();
#pragma unroll
    for (int t = 0; t < TKB; ++t) {
      float4 pa = *(const float4*)&Pl[t][ts * 8];
      float4 pc = *(const float4*)&Pl[t][ts * 8 + 4];
      float4 xa = *(const float4*)&Xl[t][td * 8];
      float4 xc = *(const float4*)&Xl[t][td * 8 + 4];
      float pv[8] = {pa.x, pa.y, pa.z, pa.w, pc.x, pc.y, pc.z, pc.w};
      float xv[8] = {xa.x, xa.y, xa.z, xa.w, xc.x, xc.y, xc.z, xc.w};
#pragma unroll
      for (int i = 0; i < 8; ++i)
#pragma unroll
        for (int jj = 0; jj < 8; ++jj)
          acc[i][jj] = fmaf(pv[i], xv[jj], acc[i][jj]);
    }
  }
#pragma unroll
  for (int i = 0; i < 8; ++i) {
    int s = s0 + ts * 8 + i;
    float sc = scale[b * T + s];
    float* op = out + ((size_t)b * T + s) * D + d0 + td * 8;
    float4 o0, o1;
    o0.x = acc[i][0] * sc; o0.y = acc[i][1] * sc; o0.z = acc[i][2] * sc; o0.w = acc[i][3] * sc;
    o1.x = acc[i][4] * sc; o1.y = acc[i][5] * sc; o1.z = acc[i][6] * sc; o1.w = acc[i][7] * sc;
    *(float4*)op = o0;
    *(float4*)(op + 4) = o1;
  }
}

extern "C" void kernel_launch(void* const* d_in, const int* in_sizes, int n_in,
                              void* d_out, int out_size, void* d_ws, size_t ws_size,
                              hipStream_t stream) {
  const float* x = (const float*)d_in[0];
  const float* y = (const float*)d_in[1];
  const float* W = (const float*)d_in[2];
  const float* bias = (const float*)d_in[3];
  const float* wscale = (const float*)d_in[4];
  const float* wshift = (const float*)d_in[5];
  float* outp = (float*)d_out;
  float* aligned = outp;                          // [B,T,D] (written last by bmm)
  float* path = outp + (size_t)NB * T * D;        // [B,T,T]
  float* distc = aligned;                         // 21 MB scratch overlaid in aligned region
  float* ws = (float*)d_ws;
  float* xw = ws;
  float* yw = xw + (size_t)NB * T * WD;
  float* scale = yw + (size_t)NB * T * WD;
  float* WeT = scale + (size_t)NB * T;
  float* beff = WeT + (size_t)WD * D;
  float* cvec = beff + WD;
  float* g = cvec + (size_t)NB * T;

  prep_kernel<<<dim3((WD * D) / 256), 256, 0, stream>>>(W, bias, wscale, wshift, WeT, beff);
  proj_kernel<<<dim3((2 * NB * T) / 64), 64, 0, stream>>>(x, y, WeT, beff, xw, yw);
  dist_kernel<<<dim3(BSTRIDE / 256, NB), 256, 0, stream>>>(xw, yw, distc);
  dtw_kernel<<<dim3(NB), 64, 0, stream>>>(distc, path);
  softmax_kernel<<<dim3(NB * T), T, 0, stream>>>(path, cvec);
  gk_kernel<<<dim3(D / 256, NB), 256, 0, stream>>>(x, cvec, g);
  colsum_kernel<<<dim3(NB), T, 0, stream>>>(path, scale);
  bmm_kernel<<<dim3(D / TDB, T / TSB, NB), 256, 0, stream>>>(path, x, cvec, g, scale, aligned);
}